// Round 4
// baseline (2742.745 us; speedup 1.0000x reference)
//
#include <hip/hip_runtime.h>
#include <cstdint>
#include <cstddef>

// ---------------------------------------------------------------------------
// SelfAttentionTransformer on MI355X (gfx950).
// L=4, D=1024, H=8, HS=128, T=1000, DFF=4096, B=8.
// R3: 512-thread 256x256 (or 128x256) GEMM with ring-3 LDS, counted vmcnt
//     (never 0 in main loop), raw s_barrier, swizzled LDS (T2), setprio (T5).
// ---------------------------------------------------------------------------

typedef unsigned short u16;
typedef unsigned int u32;
typedef __attribute__((ext_vector_type(8))) short s16x8;   // 8 bf16 raw bits
typedef __attribute__((ext_vector_type(4))) float f32x4;

#define DEV static __device__ __forceinline__

DEV float bf2f(u16 u) { union { u32 u; float f; } v; v.u = ((u32)u) << 16; return v.f; }
DEV u16 f2bf(float f) {
  union { float f; u32 u; } v; v.f = f;
  return (u16)((v.u + 0x7fffu + ((v.u >> 16) & 1u)) >> 16);   // RNE
}

#define MFMA(acc_, a_, b_) \
  asm volatile("v_mfma_f32_16x16x32_bf16 %0, %1, %2, %0" : "+v"(acc_) : "v"(a_), "v"(b_))

#define GLD16(g_, l_) \
  __builtin_amdgcn_global_load_lds((const __attribute__((address_space(1))) void*)(g_), \
                                   (__attribute__((address_space(3))) void*)(l_), 16, 0, 0)

#define BARRIER() asm volatile("s_barrier" ::: "memory")
#define VMW(n)    asm volatile("s_waitcnt vmcnt(" #n ")" ::: "memory")

static constexpr int T_ = 1000, D_ = 1024, H_ = 8, HS_ = 128, B_ = 8;
static constexpr int BT_ = B_ * T_;   // 8000

// ---------------------------------------------------------------------------
__global__ void tab_kernel(float* __restrict__ ct, float* __restrict__ st) {
  const int id = blockIdx.x * 256 + threadIdx.x;   // 64000
  const int i = id & 63, t = id >> 6;
  const float theta = powf(10000.f, -(float)i * (1.f / 64.f));
  const float ang = (float)t * theta;
  ct[id] = cosf(ang);
  st[id] = sinf(ang);
}

__global__ void convert_kernel(const float* __restrict__ in, u16* __restrict__ out, int n) {
  const int i = (blockIdx.x * 256 + threadIdx.x) * 4;
  if (i < n) {
    const float4 v = *(const float4*)(in + i);
    uint2 pk;
    pk.x = (u32)f2bf(v.x) | ((u32)f2bf(v.y) << 16);
    pk.y = (u32)f2bf(v.z) | ((u32)f2bf(v.w) << 16);
    *(uint2*)(out + i) = pk;
  }
}

// ---------------------------------------------------------------------------
// Transpose a (t,d) slice of QKVb into out[b][d][t], t zero-padded to 1024.
// ---------------------------------------------------------------------------
__global__ __launch_bounds__(256) void transpose_kernel(const u16* __restrict__ in,
                                                        u16* __restrict__ out, int cb) {
  __shared__ u16 tile[64][72];
  const int tt = blockIdx.x, dt = blockIdx.y, b = blockIdx.z;
  const int tid = threadIdx.x;
  const int r = tid >> 2, cq = (tid & 3) << 4;
  const int t = tt * 64 + r;
#pragma unroll
  for (int v = 0; v < 2; ++v) {
    s16x8 val = {};
    if (t < T_) val = *(const s16x8*)(in + (size_t)(b * 1000 + t) * 3072 + cb + dt * 64 + cq + v * 8);
    *(s16x8*)&tile[r][cq + v * 8] = val;
  }
  __syncthreads();
  const int d = dt * 64 + r;
  u16 vals[16];
#pragma unroll
  for (int j = 0; j < 16; ++j) vals[j] = tile[cq + j][r];
  u16* o = out + (size_t)b * 1048576 + (size_t)d * 1024 + tt * 64 + cq;
  *(s16x8*)o = *(s16x8*)&vals[0];
  *(s16x8*)(o + 8) = *(s16x8*)&vals[8];
}

// ---------------------------------------------------------------------------
// Deep-pipelined NT GEMM: C[m,n] = sum_k A[m,k]*B[n,k] (+bias/gelu).
// BM = BMT*128 (BMT=2: 256x256 tile, BMT=1: 128x256). BK=32, 8 waves (2x4).
// Ring-3 LDS buffers; counted vmcnt; swizzled LDS (granule ^= (row>>1)&3).
// Requires K%32==0, N%256==0. M tail via row-clamp + store guard.
// ---------------------------------------------------------------------------
template <int BMT, int BIAS, bool ACT, bool OUTBF>   // BIAS: 0 none, 2 col
__global__ __launch_bounds__(512) void gemm_nt8(
    const u16* __restrict__ A, const u16* __restrict__ B, void* __restrict__ Cv,
    const float* __restrict__ bias, int M, int N, int K, int lda, int ldb, int ldc) {
  constexpr int BM = BMT * 128;
  constexpr int MI = 4 * BMT;       // A-fragments per wave
  __shared__ alignas(16) u16 As[3][BM * 32];
  __shared__ alignas(16) u16 Bs[3][256 * 32];
  const int m0 = blockIdx.y * BM, n0 = blockIdx.x * 256;
  const int tid = threadIdx.x;
  const int wid = tid >> 6, lane = tid & 63;
  const int wr = wid >> 2, wc = wid & 3;            // 2 x 4 wave grid
  const int l15 = lane & 15, l4 = lane >> 4;

  // Staging source pointers (inverse-swizzled global source, linear LDS dest).
  const u16* pA[BMT];
  const u16* pB[2];
#pragma unroll
  for (int j = 0; j < BMT; ++j) {
    const int r = j * 128 + (tid >> 2);
    const int g = (tid & 3) ^ ((r >> 1) & 3);
    pA[j] = A + (size_t)min(m0 + r, M - 1) * lda + g * 8;
  }
#pragma unroll
  for (int j = 0; j < 2; ++j) {
    const int r = j * 128 + (tid >> 2);
    const int g = (tid & 3) ^ ((r >> 1) & 3);
    pB[j] = B + (size_t)(n0 + r) * ldb + g * 8;
  }
  // LDS fragment read offsets (elements), swizzle applied.
  int aoff[MI], boff[4];
#pragma unroll
  for (int mi = 0; mi < MI; ++mi) {
    const int row = wr * (BM / 2) + mi * 16 + l15;
    aoff[mi] = row * 32 + ((l4 ^ ((row >> 1) & 3)) * 8);
  }
#pragma unroll
  for (int ni = 0; ni < 4; ++ni) {
    const int row = wc * 64 + ni * 16 + l15;
    boff[ni] = row * 32 + ((l4 ^ ((row >> 1) & 3)) * 8);
  }

  f32x4 acc[MI][4] = {};
  const int KT = K >> 5;
  int bi = 0, sb = 2;

  auto STAGE = [&](int s) {
#pragma unroll
    for (int j = 0; j < BMT; ++j) { GLD16(pA[j], &As[s][j * 4096 + tid * 8]); pA[j] += 32; }
#pragma unroll
    for (int j = 0; j < 2; ++j) { GLD16(pB[j], &Bs[s][j * 4096 + tid * 8]); pB[j] += 32; }
  };
  auto COMPUTE = [&]() {
    const u16* Ap = &As[bi][0];
    const u16* Bp = &Bs[bi][0];
    s16x8 af[MI], bfr[4];
#pragma unroll
    for (int mi = 0; mi < MI; ++mi) af[mi] = *(const s16x8*)(Ap + aoff[mi]);
#pragma unroll
    for (int ni = 0; ni < 4; ++ni) bfr[ni] = *(const s16x8*)(Bp + boff[ni]);
    __builtin_amdgcn_s_setprio(1);
#pragma unroll
    for (int mi = 0; mi < MI; ++mi)
#pragma unroll
      for (int ni = 0; ni < 4; ++ni) MFMA(acc[mi][ni], af[mi], bfr[ni]);
    __builtin_amdgcn_s_setprio(0);
    bi = (bi == 2) ? 0 : bi + 1;
  };

  STAGE(0);
  STAGE(1);
#pragma unroll 1
  for (int kt = 0; kt < KT - 2; ++kt) {
    STAGE(sb); sb = (sb == 2) ? 0 : sb + 1;
    if constexpr (BMT == 2) { VMW(8); } else { VMW(6); }   // oldest tile resident
    BARRIER();
    COMPUTE();
    BARRIER();          // all reads of oldest buffer done -> reusable next iter
  }
  if constexpr (BMT == 2) { VMW(4); } else { VMW(3); }
  BARRIER(); COMPUTE(); BARRIER();
  VMW(0); BARRIER(); COMPUTE();

  asm volatile("s_nop 7\n\ts_nop 7"
               : "+v"(acc[MI - 1][0]), "+v"(acc[MI - 1][1]),
                 "+v"(acc[MI - 1][2]), "+v"(acc[MI - 1][3]));
#pragma unroll
  for (int mi = 0; mi < MI; ++mi) {
#pragma unroll
    for (int ni = 0; ni < 4; ++ni) {
      const int colg = n0 + wc * 64 + ni * 16 + l15;
#pragma unroll
      for (int r = 0; r < 4; ++r) {
        const int rowg = m0 + wr * (BM / 2) + mi * 16 + l4 * 4 + r;
        if (rowg < M) {
          float v = acc[mi][ni][r];
          if (BIAS == 2) v += bias[colg];
          if (ACT) v = 0.5f * v * (1.0f + erff(v * 0.70710678118654752f));
          const size_t idx = (size_t)rowg * ldc + colg;
          if (OUTBF) ((u16*)Cv)[idx] = f2bf(v);
          else       ((float*)Cv)[idx] = v;
        }
      }
    }
  }
}

// ---------------------------------------------------------------------------
// m97-style NT GEMM (256 threads) — used for the two position-mix GEMMs.
// ---------------------------------------------------------------------------
template <int BIAS, bool ACT, bool OUTBF>   // BIAS: 0 none, 1 row, 2 col
__global__ __launch_bounds__(256) void gemm_nt(
    const u16* __restrict__ A, const u16* __restrict__ B, void* __restrict__ Cv,
    const float* __restrict__ bias, int M, int N, int K, int lda, int ldb, int ldc,
    long sA, long sB, long sC) {
  __shared__ alignas(16) u16 As[128 * 32];
  __shared__ alignas(16) u16 Bs[128 * 32];
  const int z = blockIdx.z;
  A += (size_t)z * (size_t)sA;
  B += (size_t)z * (size_t)sB;
  const int m0 = blockIdx.y * 128, n0 = blockIdx.x * 128;
  const int tid = threadIdx.x;
  const int wid = tid >> 6, lane = tid & 63;
  const int wr = wid >> 1, wc = wid & 1;
  const int l15 = lane & 15, l4 = lane >> 4;
  const int srow = tid >> 2, scol = (tid & 3) << 3;
  const int mA0 = min(m0 + srow, M - 1);
  const int mA1 = min(m0 + 64 + srow, M - 1);
  const int nB0 = min(n0 + srow, N - 1);
  const int nB1 = min(n0 + 64 + srow, N - 1);
  const u16* gA0 = A + (size_t)mA0 * lda + scol;
  const u16* gA1 = A + (size_t)mA1 * lda + scol;
  const u16* gB0 = B + (size_t)nB0 * ldb + scol;
  const u16* gB1 = B + (size_t)nB1 * ldb + scol;
  u16* lA0 = As + tid * 8;  u16* lA1 = As + (256 + tid) * 8;
  u16* lB0 = Bs + tid * 8;  u16* lB1 = Bs + (256 + tid) * 8;
  f32x4 acc[4][4] = {};
  const int KT = K >> 5;
  for (int kt = 0; kt < KT; ++kt) {
    const int kb = kt << 5;
    GLD16(gA0 + kb, lA0);
    GLD16(gA1 + kb, lA1);
    GLD16(gB0 + kb, lB0);
    GLD16(gB1 + kb, lB1);
    __syncthreads();
    s16x8 af[4], bfr[4];
#pragma unroll
    for (int i = 0; i < 4; ++i)
      af[i] = *(const s16x8*)&As[(wr * 64 + i * 16 + l15) * 32 + l4 * 8];
#pragma unroll
    for (int i = 0; i < 4; ++i)
      bfr[i] = *(const s16x8*)&Bs[(wc * 64 + i * 16 + l15) * 32 + l4 * 8];
#pragma unroll
    for (int mi = 0; mi < 4; ++mi)
#pragma unroll
      for (int ni = 0; ni < 4; ++ni) MFMA(acc[mi][ni], af[mi], bfr[ni]);
    __syncthreads();
  }
  asm volatile("s_nop 7\n\ts_nop 7"
               : "+v"(acc[3][0]), "+v"(acc[3][1]), "+v"(acc[3][2]), "+v"(acc[3][3]));
#pragma unroll
  for (int mi = 0; mi < 4; ++mi) {
#pragma unroll
    for (int ni = 0; ni < 4; ++ni) {
      const int colg = n0 + wc * 64 + ni * 16 + l15;
#pragma unroll
      for (int r = 0; r < 4; ++r) {
        const int rowg = m0 + wr * 64 + mi * 16 + l4 * 4 + r;
        if (rowg < M && colg < N) {
          float v = acc[mi][ni][r];
          if (BIAS == 1) v += bias[rowg];
          if (BIAS == 2) v += bias[colg];
          if (ACT) v = 0.5f * v * (1.0f + erff(v * 0.70710678118654752f));
          const size_t idx = (size_t)z * (size_t)sC + (size_t)rowg * ldc + colg;
          if (OUTBF) ((u16*)Cv)[idx] = f2bf(v);
          else       ((float*)Cv)[idx] = v;
        }
      }
    }
  }
}

// ---------------------------------------------------------------------------
// RoPE in place, row stride ld.
// ---------------------------------------------------------------------------
__global__ __launch_bounds__(256) void rope_kernel(u16* __restrict__ X, int ld,
                                                   const float* __restrict__ ct,
                                                   const float* __restrict__ st) {
  const int id = blockIdx.x * 256 + threadIdx.x;  // 4,096,000
  const int i = id & 63;
  const int h = (id >> 6) & 7;
  const int bt = id >> 9;
  const int t = bt % 1000;
  const size_t base = (size_t)bt * ld + h * HS_ + i * 2;
  u32* p = (u32*)(X + base);
  const u32 w = *p;
  const float xr = bf2f((u16)(w & 0xffffu));
  const float xi = bf2f((u16)(w >> 16));
  const float c = ct[t * 64 + i], s = st[t * 64 + i];
  const float outr = xr * c - xi * s;
  const float outi = xr * s + xi * c;
  *p = (u32)f2bf(outr) | ((u32)f2bf(outi) << 16);
}

// ---------------------------------------------------------------------------
// Flash attention (non-causal), QBLK=128 (4 waves x 32 q-rows), KVBLK=64.
// ---------------------------------------------------------------------------
__global__ __launch_bounds__(256) void attn_kernel(const u16* __restrict__ Q, int ldq,
                                                   const u16* __restrict__ Km,
                                                   const u16* __restrict__ Vmt,
                                                   float* __restrict__ Y) {
  __shared__ alignas(16) u16 Ks[64][136];
  __shared__ alignas(16) u16 Vts[128][72];
  __shared__ alignas(16) u16 Ps[4][32][72];
  const int qt = blockIdx.x;
  const int bh = blockIdx.y;
  const int b = bh >> 3, h = bh & 7;
  const int tid = threadIdx.x;
  const int w = tid >> 6, lane = tid & 63;
  const int l15 = lane & 15, l4 = lane >> 4;
  const size_t qbase = (size_t)b * 1000 * ldq + h * HS_;
  const size_t kbase = (size_t)b * 1024000 + h * HS_;
  const size_t vbase = (size_t)b * 1048576 + (size_t)(h * HS_) * 1024;
  const int q0 = qt * 128 + w * 32;
  s16x8 aq[2][4];
#pragma unroll
  for (int qf = 0; qf < 2; ++qf) {
    const int qrow = q0 + qf * 16 + l15;
#pragma unroll
    for (int c = 0; c < 4; ++c) {
      s16x8 v = {};
      if (qrow < T_) v = *(const s16x8*)(Q + qbase + (size_t)qrow * ldq + c * 32 + l4 * 8);
      aq[qf][c] = v;
    }
  }
  f32x4 acc[2][8] = {};
  float m_run[2][4], l_run[2][4];
#pragma unroll
  for (int qf = 0; qf < 2; ++qf)
#pragma unroll
    for (int r = 0; r < 4; ++r) { m_run[qf][r] = -1e30f; l_run[qf][r] = 0.f; }
  const float SCALE = 0.08838834764831845f;
  for (int kt = 0; kt < 16; ++kt) {
    {
      const int r = tid >> 2, c0 = (tid & 3) << 5;
      const int kk = kt * 64 + r;
#pragma unroll
      for (int v = 0; v < 4; ++v) {
        s16x8 val = {};
        if (kk < T_) val = *(const s16x8*)(Km + kbase + (size_t)kk * 1024 + c0 + v * 8);
        *(s16x8*)&Ks[r][c0 + v * 8] = val;
      }
      const int r2 = tid >> 1, c2s = (tid & 1) << 5;
#pragma unroll
      for (int v = 0; v < 4; ++v) {
        const s16x8 val = *(const s16x8*)(Vmt + vbase + (size_t)r2 * 1024 + kt * 64 + c2s + v * 8);
        *(s16x8*)&Vts[r2][c2s + v * 8] = val;
      }
    }
    __syncthreads();
    f32x4 sacc[2][4] = {};
#pragma unroll
    for (int c = 0; c < 4; ++c) {
      s16x8 bk[4];
#pragma unroll
      for (int f = 0; f < 4; ++f) bk[f] = *(const s16x8*)&Ks[f * 16 + l15][c * 32 + l4 * 8];
#pragma unroll
      for (int qf = 0; qf < 2; ++qf)
#pragma unroll
        for (int f = 0; f < 4; ++f) MFMA(sacc[qf][f], aq[qf][c], bk[f]);
    }
    asm volatile("s_nop 7\n\ts_nop 7"
                 : "+v"(sacc[0][0]), "+v"(sacc[0][1]), "+v"(sacc[0][2]), "+v"(sacc[0][3]),
                   "+v"(sacc[1][0]), "+v"(sacc[1][1]), "+v"(sacc[1][2]), "+v"(sacc[1][3]));
#pragma unroll
    for (int qf = 0; qf < 2; ++qf) {
      float sv[4][4];
#pragma unroll
      for (int f = 0; f < 4; ++f) {
        const int key = kt * 64 + f * 16 + l15;
#pragma unroll
        for (int r = 0; r < 4; ++r) sv[f][r] = (key < T_) ? sacc[qf][f][r] * SCALE : -1e30f;
      }
#pragma unroll
      for (int r = 0; r < 4; ++r) {
        float mx = fmaxf(fmaxf(sv[0][r], sv[1][r]), fmaxf(sv[2][r], sv[3][r]));
#pragma unroll
        for (int off = 8; off >= 1; off >>= 1) mx = fmaxf(mx, __shfl_xor(mx, off));
        const float mn = fmaxf(m_run[qf][r], mx);
        const float corr = __expf(m_run[qf][r] - mn);
        m_run[qf][r] = mn;
        float rs = 0.f;
#pragma unroll
        for (int f = 0; f < 4; ++f) {
          const float p = __expf(sv[f][r] - mn);
          rs += p;
          Ps[w][qf * 16 + l4 * 4 + r][f * 16 + l15] = f2bf(p);
        }
#pragma unroll
        for (int off = 8; off >= 1; off >>= 1) rs += __shfl_xor(rs, off);
        l_run[qf][r] = l_run[qf][r] * corr + rs;
#pragma unroll
        for (int n = 0; n < 8; ++n) acc[qf][n][r] *= corr;
      }
    }
    asm volatile("s_waitcnt lgkmcnt(0)" ::: "memory");
#pragma unroll
    for (int c2 = 0; c2 < 2; ++c2) {
      s16x8 pa[2];
#pragma unroll
      for (int qf = 0; qf < 2; ++qf)
        pa[qf] = *(const s16x8*)&Ps[w][qf * 16 + l15][c2 * 32 + l4 * 8];
#pragma unroll
      for (int n = 0; n < 8; ++n) {
        const s16x8 vb = *(const s16x8*)&Vts[n * 16 + l15][c2 * 32 + l4 * 8];
#pragma unroll
        for (int qf = 0; qf < 2; ++qf) MFMA(acc[qf][n], pa[qf], vb);
      }
    }
    __syncthreads();
  }
  asm volatile("s_nop 7\n\ts_nop 7"
               : "+v"(acc[0][6]), "+v"(acc[0][7]), "+v"(acc[1][6]), "+v"(acc[1][7]));
#pragma unroll
  for (int qf = 0; qf < 2; ++qf)
#pragma unroll
    for (int n = 0; n < 8; ++n)
#pragma unroll
      for (int r = 0; r < 4; ++r) {
        const int q = q0 + qf * 16 + l4 * 4 + r;
        if (q < T_)
          Y[(size_t)(b * 1000 + q) * 1024 + h * HS_ + n * 16 + l15] = acc[qf][n][r] / l_run[qf][r];
      }
}

// ---------------------------------------------------------------------------
// src = LN(src + add) * g + b  (fp32 master) + bf16 mirror.
// ---------------------------------------------------------------------------
__global__ __launch_bounds__(256) void addln_kernel(float* __restrict__ src,
                                                    const float* __restrict__ add,
                                                    const float* __restrict__ g,
                                                    const float* __restrict__ bb,
                                                    u16* __restrict__ outb) {
  const int row = blockIdx.x;
  const int tid = threadIdx.x;
  float* s = src + (size_t)row * D_;
  const float* a = add + (size_t)row * D_;
  float x[4];
  float sum = 0.f, sq = 0.f;
#pragma unroll
  for (int i = 0; i < 4; ++i) {
    const int d = tid + i * 256;
    const float v = s[d] + a[d];
    x[i] = v; sum += v; sq += v * v;
  }
#pragma unroll
  for (int off = 32; off >= 1; off >>= 1) { sum += __shfl_xor(sum, off); sq += __shfl_xor(sq, off); }
  __shared__ float red[8];
  const int wid = tid >> 6;
  if ((tid & 63) == 0) { red[wid] = sum; red[4 + wid] = sq; }
  __syncthreads();
  sum = red[0] + red[1] + red[2] + red[3];
  sq = red[4] + red[5] + red[6] + red[7];
  const float mean = sum * (1.f / 1024.f);
  const float var = sq * (1.f / 1024.f) - mean * mean;
  const float rstd = rsqrtf(var + 1e-5f);
#pragma unroll
  for (int i = 0; i < 4; ++i) {
    const int d = tid + i * 256;
    const float y = (x[i] - mean) * rstd * g[d] + bb[d];
    s[d] = y;
    outb[(size_t)row * D_ + d] = f2bf(y);
  }
}

// ---------------------------------------------------------------------------
// Host orchestration
// ---------------------------------------------------------------------------
static inline int cdiv(int a, int b) { return (a + b - 1) / b; }

extern "C" void kernel_launch(void* const* d_in, const int* in_sizes, int n_in,
                              void* d_out, int out_size, void* d_ws, size_t ws_size,
                              hipStream_t stream) {
  const float* x    = (const float*)d_in[0];
  const float* Wq   = (const float*)d_in[1];
  const float* Wk   = (const float*)d_in[2];
  const float* Wv   = (const float*)d_in[3];
  const float* Wpk  = (const float*)d_in[4];
  const float* bpk  = (const float*)d_in[5];
  const float* Wpv  = (const float*)d_in[6];
  const float* bpv  = (const float*)d_in[7];
  const float* g1   = (const float*)d_in[8];
  const float* b1ln = (const float*)d_in[9];
  const float* W1   = (const float*)d_in[10];
  const float* b1   = (const float*)d_in[11];
  const float* W2   = (const float*)d_in[12];
  const float* b2   = (const float*)d_in[13];
  const float* g2   = (const float*)d_in[14];
  const float* b2ln = (const float*)d_in[15];

  char* wsb = (char*)d_ws;
  float* cosT = (float*)(wsb + 0);                //   256 KB
  float* sinT = (float*)(wsb + 262144);           //   256 KB
  float* srcf = (float*)(wsb + 524288);           // 32.77 MB fp32 residual
  u16* srcb   = (u16*)(wsb + 33292288);           // 16.38 MB bf16 mirror
  u16* QKVb   = (u16*)(wsb + 49676288);           // 49.15 MB [8000][3072]
  u16* Ttmp   = (u16*)(wsb + 98828288);           // 16.78 MB [8][1024][1024]
  u16* Km     = (u16*)(wsb + 115605504);          // 16.38 MB [8][1000][1024]
  u16* Vmt    = (u16*)(wsb + 131989504);          // 16.78 MB [8][1024 d][1024 keys]
  u16* wbuf   = (u16*)(wsb + 148766720);          // 27.07 MB layer weights
  u16* hB     = QKVb;  // [8000][4096] overlaps QKVb+Ttmp (dead at FFN time)

  u16* wqB  = wbuf + 0;          // [3072][1024] fused q,k,v
  u16* wpkB = wbuf + 3145728;    // [1000][1000]
  u16* wpvB = wbuf + 4145728;
  u16* w1B  = wbuf + 5145728;    // [4096][1024]
  u16* w2B  = wbuf + 9340032;    // [1024][4096]

  float* yF = (float*)d_out;

  tab_kernel<<<250, 256, 0, stream>>>(cosT, sinT);
  hipMemcpyAsync(srcf, x, (size_t)BT_ * D_ * sizeof(float), hipMemcpyDeviceToDevice, stream);
  convert_kernel<<<cdiv(BT_ * D_, 1024), 256, 0, stream>>>(x, srcb, BT_ * D_);

  for (int l = 0; l < 4; ++l) {
    convert_kernel<<<cdiv(1048576, 1024), 256, 0, stream>>>(Wq + (size_t)l * 1048576, wqB, 1048576);
    convert_kernel<<<cdiv(1048576, 1024), 256, 0, stream>>>(Wk + (size_t)l * 1048576, wqB + 1048576, 1048576);
    convert_kernel<<<cdiv(1048576, 1024), 256, 0, stream>>>(Wv + (size_t)l * 1048576, wqB + 2097152, 1048576);
    convert_kernel<<<cdiv(1000000, 1024), 256, 0, stream>>>(Wpk + (size_t)l * 1000000, wpkB, 1000000);
    convert_kernel<<<cdiv(1000000, 1024), 256, 0, stream>>>(Wpv + (size_t)l * 1000000, wpvB, 1000000);
    convert_kernel<<<cdiv(4194304, 1024), 256, 0, stream>>>(W1 + (size_t)l * 4194304, w1B, 4194304);
    convert_kernel<<<cdiv(4194304, 1024), 256, 0, stream>>>(W2 + (size_t)l * 4194304, w2B, 4194304);

    // Fused QKV: (8000x3072) = srcb x [Wq;Wk;Wv]^T   [256x256 tiles]
    gemm_nt8<2, 0, false, true><<<dim3(12, 32), 512, 0, stream>>>(
        srcb, wqB, QKVb, nullptr, BT_, 3072, 1024, 1024, 1024, 3072);

    // K position-mix via transpose + NT GEMM (m97-style path)
    transpose_kernel<<<dim3(16, 16, 8), 256, 0, stream>>>(QKVb, Ttmp, 1024);
    gemm_nt<1, false, true><<<dim3(8, 8, 8), 256, 0, stream>>>(
        wpkB, Ttmp, Km, bpk + (size_t)l * 1000, 1000, 1024, 1024,
        1000, 1024, 1024, 0L, 1048576L, 1024000L);

    // V position-mix (transposed output)
    transpose_kernel<<<dim3(16, 16, 8), 256, 0, stream>>>(QKVb, Ttmp, 2048);
    gemm_nt<2, false, true><<<dim3(8, 8, 8), 256, 0, stream>>>(
        Ttmp, wpvB, Vmt, bpv + (size_t)l * 1000, 1024, 1000, 1024,
        1024, 1000, 1024, 1048576L, 0L, 1048576L);

    rope_kernel<<<16000, 256, 0, stream>>>(QKVb, 3072, cosT, sinT);  // Q
    rope_kernel<<<16000, 256, 0, stream>>>(Km, 1024, cosT, sinT);

    attn_kernel<<<dim3(8, 64), 256, 0, stream>>>(QKVb, 3072, Km, Vmt, yF);

    addln_kernel<<<BT_, 256, 0, stream>>>(srcf, yF, g1 + (size_t)l * 1024,
                                          b1ln + (size_t)l * 1024, srcb);

    // FFN1 (+bias+gelu) -> bf16 h   [256x256 tiles]
    gemm_nt8<2, 2, true, true><<<dim3(16, 32), 512, 0, stream>>>(
        srcb, w1B, hB, b1 + (size_t)l * 4096, BT_, 4096, 1024, 1024, 1024, 4096);
    // FFN2 (+bias) -> fp32 d_out    [128x256 tiles for grid occupancy]
    gemm_nt8<1, 2, false, false><<<dim3(4, 63), 512, 0, stream>>>(
        hB, w2B, d_out, b2 + (size_t)l * 1024, BT_, 1024, 4096, 4096, 4096, 1024);

    addln_kernel<<<BT_, 256, 0, stream>>>(srcf, yF, g2 + (size_t)l * 1024,
                                          b2ln + (size_t)l * 1024, srcb);
  }

  hipMemcpyAsync(d_out, srcf, (size_t)BT_ * D_ * sizeof(float), hipMemcpyDeviceToDevice, stream);
}

// Round 5
// 2583.577 us; speedup vs baseline: 1.0616x; 1.0616x over previous
//
#include <hip/hip_runtime.h>
#include <cstdint>
#include <cstddef>

// ---------------------------------------------------------------------------
// SelfAttentionTransformer on MI355X (gfx950).
// L=4, D=1024, H=8, HS=128, T=1000, DFF=4096, B=8.
// R4: fine-phase 256x256 GEMM (BK=32, 2 LDS bufs, 2 phases/K-tile,
//     counted vmcnt(2), dual barriers/phase, swizzled LDS, setprio)
//     for QKV + FFN1. FFN2/mixes stay on proven m97-style gemm_nt.
// ---------------------------------------------------------------------------

typedef unsigned short u16;
typedef unsigned int u32;
typedef __attribute__((ext_vector_type(8))) short s16x8;   // 8 bf16 raw bits
typedef __attribute__((ext_vector_type(4))) float f32x4;

#define DEV static __device__ __forceinline__

DEV float bf2f(u16 u) { union { u32 u; float f; } v; v.u = ((u32)u) << 16; return v.f; }
DEV u16 f2bf(float f) {
  union { float f; u32 u; } v; v.f = f;
  return (u16)((v.u + 0x7fffu + ((v.u >> 16) & 1u)) >> 16);   // RNE
}

#define MFMA(acc_, a_, b_) \
  asm volatile("v_mfma_f32_16x16x32_bf16 %0, %1, %2, %0" : "+v"(acc_) : "v"(a_), "v"(b_))

#define GLD16(g_, l_) \
  __builtin_amdgcn_global_load_lds((const __attribute__((address_space(1))) void*)(g_), \
                                   (__attribute__((address_space(3))) void*)(l_), 16, 0, 0)

#define BARRIER() asm volatile("s_barrier" ::: "memory")
#define VMW(n)    asm volatile("s_waitcnt vmcnt(" #n ")" ::: "memory")

static constexpr int T_ = 1000, D_ = 1024, H_ = 8, HS_ = 128, B_ = 8;
static constexpr int BT_ = B_ * T_;   // 8000

// ---------------------------------------------------------------------------
__global__ void tab_kernel(float* __restrict__ ct, float* __restrict__ st) {
  const int id = blockIdx.x * 256 + threadIdx.x;   // 64000
  const int i = id & 63, t = id >> 6;
  const float theta = powf(10000.f, -(float)i * (1.f / 64.f));
  const float ang = (float)t * theta;
  ct[id] = cosf(ang);
  st[id] = sinf(ang);
}

__global__ void convert_kernel(const float* __restrict__ in, u16* __restrict__ out, int n) {
  const int i = (blockIdx.x * 256 + threadIdx.x) * 4;
  if (i < n) {
    const float4 v = *(const float4*)(in + i);
    uint2 pk;
    pk.x = (u32)f2bf(v.x) | ((u32)f2bf(v.y) << 16);
    pk.y = (u32)f2bf(v.z) | ((u32)f2bf(v.w) << 16);
    *(uint2*)(out + i) = pk;
  }
}

// ---------------------------------------------------------------------------
// Transpose a (t,d) slice of QKVb into out[b][d][t], t zero-padded to 1024.
// ---------------------------------------------------------------------------
__global__ __launch_bounds__(256) void transpose_kernel(const u16* __restrict__ in,
                                                        u16* __restrict__ out, int cb) {
  __shared__ u16 tile[64][72];
  const int tt = blockIdx.x, dt = blockIdx.y, b = blockIdx.z;
  const int tid = threadIdx.x;
  const int r = tid >> 2, cq = (tid & 3) << 4;
  const int t = tt * 64 + r;
#pragma unroll
  for (int v = 0; v < 2; ++v) {
    s16x8 val = {};
    if (t < T_) val = *(const s16x8*)(in + (size_t)(b * 1000 + t) * 3072 + cb + dt * 64 + cq + v * 8);
    *(s16x8*)&tile[r][cq + v * 8] = val;
  }
  __syncthreads();
  const int d = dt * 64 + r;
  u16 vals[16];
#pragma unroll
  for (int j = 0; j < 16; ++j) vals[j] = tile[cq + j][r];
  u16* o = out + (size_t)b * 1048576 + (size_t)d * 1024 + tt * 64 + cq;
  *(s16x8*)o = *(s16x8*)&vals[0];
  *(s16x8*)(o + 8) = *(s16x8*)&vals[8];
}

// ---------------------------------------------------------------------------
// Fine-phase 256x256 NT GEMM. C[m,n] = sum_k A[m,k]*B[n,k] (+bias/gelu).
// BK=32, 512 threads (8 waves, 2Mx4N), 2 LDS K-tile buffers (64 KB total).
// Per K-tile: 2 phases x {ds_read | stage 2 GLD | barrier | 16 MFMA | barrier}.
// vmcnt(2) once per tile (never 0). LDS swizzle: granule ^= (row>>1)&3,
// inverse-applied on global source (linear LDS dest), same XOR on reads.
// Requires K%32==0, N%256==0; M tail via clamp + store guard.
// ---------------------------------------------------------------------------
template <int BIAS, bool ACT, bool OUTBF>   // BIAS: 0 none, 2 col
__global__ __launch_bounds__(512) void gemm8p(
    const u16* __restrict__ A, const u16* __restrict__ B, void* __restrict__ Cv,
    const float* __restrict__ bias, int M, int N, int K, int lda, int ldb, int ldc) {
  __shared__ alignas(16) u16 lds[2][16384];   // per buf: A[256][32] | B[256][32]
  const int m0 = blockIdx.y * 256, n0 = blockIdx.x * 256;
  const int tid = threadIdx.x;
  const int lane = tid & 63, wid = tid >> 6;
  const int wr = wid >> 2, wc = wid & 3;            // 2 x 4 wave grid
  const int l15 = lane & 15, l4 = lane >> 4;

  // Staging: 512 threads x 16B = 128 rows/line. Source granule pre-swizzled.
  const int srow = tid >> 2;
  const int sg = ((tid & 3) ^ ((tid >> 3) & 3)) * 8;
  const u16* gA0 = A + (size_t)min(m0 + srow, M - 1) * lda + sg;
  const u16* gA1 = A + (size_t)min(m0 + 128 + srow, M - 1) * lda + sg;
  const u16* gB0 = B + (size_t)min(n0 + srow, N - 1) * ldb + sg;
  const u16* gB1 = B + (size_t)min(n0 + 128 + srow, N - 1) * ldb + sg;

  // Fragment read bases (u16 elements), swizzle XOR on the 16B granule.
  const int gg = (l4 ^ ((l15 >> 1) & 3)) * 8;
  const int aBase = (wr * 128 + l15) * 32 + gg;
  const int bBase = 8192 + (wc * 64 + l15) * 32 + gg;

  f32x4 acc[8][4] = {};
  const int KT = K >> 5;
  const int kLast = K - 32;

  // Prologue: T0 full -> buf0; B of T1 -> buf1.  [6 GLD issued]
  GLD16(gA0, &lds[0][0] + tid * 8);
  GLD16(gA1, &lds[0][4096] + tid * 8);
  GLD16(gB0, &lds[0][8192] + tid * 8);
  GLD16(gB1, &lds[0][12288] + tid * 8);
  {
    const int kb = min(32, kLast);
    GLD16(gB0 + kb, &lds[1][8192] + tid * 8);
    GLD16(gB1 + kb, &lds[1][12288] + tid * 8);
  }
  VMW(2);       // T0 resident (newest 2 = B of T1 may be in flight)
  BARRIER();

  int c = 0;
#pragma unroll 1
  for (int m = 0; m < KT; ++m) {
    const u16* Lc = &lds[c][0];
    // ---- Phase 1: frags(mh0) + B-frags; stage A of T(m+1) into other buf ----
    s16x8 af[4], bf4[4];
#pragma unroll
    for (int mi = 0; mi < 4; ++mi) af[mi] = *(const s16x8*)(Lc + aBase + mi * 512);
#pragma unroll
    for (int ni = 0; ni < 4; ++ni) bf4[ni] = *(const s16x8*)(Lc + bBase + ni * 512);
    {
      const int kb = min((m + 1) << 5, kLast);
      GLD16(gA0 + kb, &lds[c ^ 1][0] + tid * 8);
      GLD16(gA1 + kb, &lds[c ^ 1][4096] + tid * 8);
    }
    BARRIER();
    __builtin_amdgcn_s_setprio(1);
#pragma unroll
    for (int mi = 0; mi < 4; ++mi)
#pragma unroll
      for (int ni = 0; ni < 4; ++ni) MFMA(acc[mi][ni], af[mi], bf4[ni]);
    __builtin_amdgcn_s_setprio(0);
    BARRIER();
    // ---- Phase 2: frags(mh1); stage B of T(m+2) into current buf ----
    s16x8 ag[4];
#pragma unroll
    for (int mi = 0; mi < 4; ++mi) ag[mi] = *(const s16x8*)(Lc + aBase + 2048 + mi * 512);
    {
      const int kb = min((m + 2) << 5, kLast);
      GLD16(gB0 + kb, &lds[c][8192] + tid * 8);
      GLD16(gB1 + kb, &lds[c][12288] + tid * 8);
    }
    VMW(2);     // retire all but newest 2 -> T(m+1) fully resident
    BARRIER();
    __builtin_amdgcn_s_setprio(1);
#pragma unroll
    for (int mi = 0; mi < 4; ++mi)
#pragma unroll
      for (int ni = 0; ni < 4; ++ni) MFMA(acc[4 + mi][ni], ag[mi], bf4[ni]);
    __builtin_amdgcn_s_setprio(0);
    BARRIER();
    c ^= 1;
  }

  asm volatile("s_nop 7\n\ts_nop 7"
               : "+v"(acc[7][0]), "+v"(acc[7][1]), "+v"(acc[7][2]), "+v"(acc[7][3]));
#pragma unroll
  for (int mi = 0; mi < 8; ++mi) {
#pragma unroll
    for (int ni = 0; ni < 4; ++ni) {
      const int colg = n0 + wc * 64 + ni * 16 + l15;
#pragma unroll
      for (int r = 0; r < 4; ++r) {
        const int rowg = m0 + wr * 128 + mi * 16 + l4 * 4 + r;
        if (rowg < M) {
          float v = acc[mi][ni][r];
          if (BIAS == 2) v += bias[colg];
          if (ACT) v = 0.5f * v * (1.0f + erff(v * 0.70710678118654752f));
          const size_t idx = (size_t)rowg * ldc + colg;
          if (OUTBF) ((u16*)Cv)[idx] = f2bf(v);
          else       ((float*)Cv)[idx] = v;
        }
      }
    }
  }
}

// ---------------------------------------------------------------------------
// m97-style NT GEMM (256 threads) — mixes and FFN2.
// ---------------------------------------------------------------------------
template <int BIAS, bool ACT, bool OUTBF>   // BIAS: 0 none, 1 row, 2 col
__global__ __launch_bounds__(256) void gemm_nt(
    const u16* __restrict__ A, const u16* __restrict__ B, void* __restrict__ Cv,
    const float* __restrict__ bias, int M, int N, int K, int lda, int ldb, int ldc,
    long sA, long sB, long sC) {
  __shared__ alignas(16) u16 As[128 * 32];
  __shared__ alignas(16) u16 Bs[128 * 32];
  const int z = blockIdx.z;
  A += (size_t)z * (size_t)sA;
  B += (size_t)z * (size_t)sB;
  const int m0 = blockIdx.y * 128, n0 = blockIdx.x * 128;
  const int tid = threadIdx.x;
  const int wid = tid >> 6, lane = tid & 63;
  const int wr = wid >> 1, wc = wid & 1;
  const int l15 = lane & 15, l4 = lane >> 4;
  const int srow = tid >> 2, scol = (tid & 3) << 3;
  const int mA0 = min(m0 + srow, M - 1);
  const int mA1 = min(m0 + 64 + srow, M - 1);
  const int nB0 = min(n0 + srow, N - 1);
  const int nB1 = min(n0 + 64 + srow, N - 1);
  const u16* gA0 = A + (size_t)mA0 * lda + scol;
  const u16* gA1 = A + (size_t)mA1 * lda + scol;
  const u16* gB0 = B + (size_t)nB0 * ldb + scol;
  const u16* gB1 = B + (size_t)nB1 * ldb + scol;
  u16* lA0 = As + tid * 8;  u16* lA1 = As + (256 + tid) * 8;
  u16* lB0 = Bs + tid * 8;  u16* lB1 = Bs + (256 + tid) * 8;
  f32x4 acc[4][4] = {};
  const int KT = K >> 5;
  for (int kt = 0; kt < KT; ++kt) {
    const int kb = kt << 5;
    GLD16(gA0 + kb, lA0);
    GLD16(gA1 + kb, lA1);
    GLD16(gB0 + kb, lB0);
    GLD16(gB1 + kb, lB1);
    __syncthreads();
    s16x8 af[4], bfr[4];
#pragma unroll
    for (int i = 0; i < 4; ++i)
      af[i] = *(const s16x8*)&As[(wr * 64 + i * 16 + l15) * 32 + l4 * 8];
#pragma unroll
    for (int i = 0; i < 4; ++i)
      bfr[i] = *(const s16x8*)&Bs[(wc * 64 + i * 16 + l15) * 32 + l4 * 8];
#pragma unroll
    for (int mi = 0; mi < 4; ++mi)
#pragma unroll
      for (int ni = 0; ni < 4; ++ni) MFMA(acc[mi][ni], af[mi], bfr[ni]);
    __syncthreads();
  }
  asm volatile("s_nop 7\n\ts_nop 7"
               : "+v"(acc[3][0]), "+v"(acc[3][1]), "+v"(acc[3][2]), "+v"(acc[3][3]));
#pragma unroll
  for (int mi = 0; mi < 4; ++mi) {
#pragma unroll
    for (int ni = 0; ni < 4; ++ni) {
      const int colg = n0 + wc * 64 + ni * 16 + l15;
#pragma unroll
      for (int r = 0; r < 4; ++r) {
        const int rowg = m0 + wr * 64 + mi * 16 + l4 * 4 + r;
        if (rowg < M && colg < N) {
          float v = acc[mi][ni][r];
          if (BIAS == 1) v += bias[rowg];
          if (BIAS == 2) v += bias[colg];
          if (ACT) v = 0.5f * v * (1.0f + erff(v * 0.70710678118654752f));
          const size_t idx = (size_t)z * (size_t)sC + (size_t)rowg * ldc + colg;
          if (OUTBF) ((u16*)Cv)[idx] = f2bf(v);
          else       ((float*)Cv)[idx] = v;
        }
      }
    }
  }
}

// ---------------------------------------------------------------------------
// RoPE in place, row stride ld.
// ---------------------------------------------------------------------------
__global__ __launch_bounds__(256) void rope_kernel(u16* __restrict__ X, int ld,
                                                   const float* __restrict__ ct,
                                                   const float* __restrict__ st) {
  const int id = blockIdx.x * 256 + threadIdx.x;  // 4,096,000
  const int i = id & 63;
  const int h = (id >> 6) & 7;
  const int bt = id >> 9;
  const int t = bt % 1000;
  const size_t base = (size_t)bt * ld + h * HS_ + i * 2;
  u32* p = (u32*)(X + base);
  const u32 w = *p;
  const float xr = bf2f((u16)(w & 0xffffu));
  const float xi = bf2f((u16)(w >> 16));
  const float c = ct[t * 64 + i], s = st[t * 64 + i];
  const float outr = xr * c - xi * s;
  const float outi = xr * s + xi * c;
  *p = (u32)f2bf(outr) | ((u32)f2bf(outi) << 16);
}

// ---------------------------------------------------------------------------
// Flash attention (non-causal), QBLK=128 (4 waves x 32 q-rows), KVBLK=64.
// ---------------------------------------------------------------------------
__global__ __launch_bounds__(256) void attn_kernel(const u16* __restrict__ Q, int ldq,
                                                   const u16* __restrict__ Km,
                                                   const u16* __restrict__ Vmt,
                                                   float* __restrict__ Y) {
  __shared__ alignas(16) u16 Ks[64][136];
  __shared__ alignas(16) u16 Vts[128][72];
  __shared__ alignas(16) u16 Ps[4][32][72];
  const int qt = blockIdx.x;
  const int bh = blockIdx.y;
  const int b = bh >> 3, h = bh & 7;
  const int tid = threadIdx.x;
  const int w = tid >> 6, lane = tid & 63;
  const int l15 = lane & 15, l4 = lane >> 4;
  const size_t qbase = (size_t)b * 1000 * ldq + h * HS_;
  const size_t kbase = (size_t)b * 1024000 + h * HS_;
  const size_t vbase = (size_t)b * 1048576 + (size_t)(h * HS_) * 1024;
  const int q0 = qt * 128 + w * 32;
  s16x8 aq[2][4];
#pragma unroll
  for (int qf = 0; qf < 2; ++qf) {
    const int qrow = q0 + qf * 16 + l15;
#pragma unroll
    for (int c = 0; c < 4; ++c) {
      s16x8 v = {};
      if (qrow < T_) v = *(const s16x8*)(Q + qbase + (size_t)qrow * ldq + c * 32 + l4 * 8);
      aq[qf][c] = v;
    }
  }
  f32x4 acc[2][8] = {};
  float m_run[2][4], l_run[2][4];
#pragma unroll
  for (int qf = 0; qf < 2; ++qf)
#pragma unroll
    for (int r = 0; r < 4; ++r) { m_run[qf][r] = -1e30f; l_run[qf][r] = 0.f; }
  const float SCALE = 0.08838834764831845f;
  for (int kt = 0; kt < 16; ++kt) {
    {
      const int r = tid >> 2, c0 = (tid & 3) << 5;
      const int kk = kt * 64 + r;
#pragma unroll
      for (int v = 0; v < 4; ++v) {
        s16x8 val = {};
        if (kk < T_) val = *(const s16x8*)(Km + kbase + (size_t)kk * 1024 + c0 + v * 8);
        *(s16x8*)&Ks[r][c0 + v * 8] = val;
      }
      const int r2 = tid >> 1, c2s = (tid & 1) << 5;
#pragma unroll
      for (int v = 0; v < 4; ++v) {
        const s16x8 val = *(const s16x8*)(Vmt + vbase + (size_t)r2 * 1024 + kt * 64 + c2s + v * 8);
        *(s16x8*)&Vts[r2][c2s + v * 8] = val;
      }
    }
    __syncthreads();
    f32x4 sacc[2][4] = {};
#pragma unroll
    for (int c = 0; c < 4; ++c) {
      s16x8 bk[4];
#pragma unroll
      for (int f = 0; f < 4; ++f) bk[f] = *(const s16x8*)&Ks[f * 16 + l15][c * 32 + l4 * 8];
#pragma unroll
      for (int qf = 0; qf < 2; ++qf)
#pragma unroll
        for (int f = 0; f < 4; ++f) MFMA(sacc[qf][f], aq[qf][c], bk[f]);
    }
    asm volatile("s_nop 7\n\ts_nop 7"
                 : "+v"(sacc[0][0]), "+v"(sacc[0][1]), "+v"(sacc[0][2]), "+v"(sacc[0][3]),
                   "+v"(sacc[1][0]), "+v"(sacc[1][1]), "+v"(sacc[1][2]), "+v"(sacc[1][3]));
#pragma unroll
    for (int qf = 0; qf < 2; ++qf) {
      float sv[4][4];
#pragma unroll
      for (int f = 0; f < 4; ++f) {
        const int key = kt * 64 + f * 16 + l15;
#pragma unroll
        for (int r = 0; r < 4; ++r) sv[f][r] = (key < T_) ? sacc[qf][f][r] * SCALE : -1e30f;
      }
#pragma unroll
      for (int r = 0; r < 4; ++r) {
        float mx = fmaxf(fmaxf(sv[0][r], sv[1][r]), fmaxf(sv[2][r], sv[3][r]));
#pragma unroll
        for (int off = 8; off >= 1; off >>= 1) mx = fmaxf(mx, __shfl_xor(mx, off));
        const float mn = fmaxf(m_run[qf][r], mx);
        const float corr = __expf(m_run[qf][r] - mn);
        m_run[qf][r] = mn;
        float rs = 0.f;
#pragma unroll
        for (int f = 0; f < 4; ++f) {
          const float p = __expf(sv[f][r] - mn);
          rs += p;
          Ps[w][qf * 16 + l4 * 4 + r][f * 16 + l15] = f2bf(p);
        }
#pragma unroll
        for (int off = 8; off >= 1; off >>= 1) rs += __shfl_xor(rs, off);
        l_run[qf][r] = l_run[qf][r] * corr + rs;
#pragma unroll
        for (int n = 0; n < 8; ++n) acc[qf][n][r] *= corr;
      }
    }
    asm volatile("s_waitcnt lgkmcnt(0)" ::: "memory");
#pragma unroll
    for (int c2 = 0; c2 < 2; ++c2) {
      s16x8 pa[2];
#pragma unroll
      for (int qf = 0; qf < 2; ++qf)
        pa[qf] = *(const s16x8*)&Ps[w][qf * 16 + l15][c2 * 32 + l4 * 8];
#pragma unroll
      for (int n = 0; n < 8; ++n) {
        const s16x8 vb = *(const s16x8*)&Vts[n * 16 + l15][c2 * 32 + l4 * 8];
#pragma unroll
        for (int qf = 0; qf < 2; ++qf) MFMA(acc[qf][n], pa[qf], vb);
      }
    }
    __syncthreads();
  }
  asm volatile("s_nop 7\n\ts_nop 7"
               : "+v"(acc[0][6]), "+v"(acc[0][7]), "+v"(acc[1][6]), "+v"(acc[1][7]));
#pragma unroll
  for (int qf = 0; qf < 2; ++qf)
#pragma unroll
    for (int n = 0; n < 8; ++n)
#pragma unroll
      for (int r = 0; r < 4; ++r) {
        const int q = q0 + qf * 16 + l4 * 4 + r;
        if (q < T_)
          Y[(size_t)(b * 1000 + q) * 1024 + h * HS_ + n * 16 + l15] = acc[qf][n][r] / l_run[qf][r];
      }
}

// ---------------------------------------------------------------------------
// src = LN(src + add) * g + b  (fp32 master) + bf16 mirror.
// ---------------------------------------------------------------------------
__global__ __launch_bounds__(256) void addln_kernel(float* __restrict__ src,
                                                    const float* __restrict__ add,
                                                    const float* __restrict__ g,
                                                    const float* __restrict__ bb,
                                                    u16* __restrict__ outb) {
  const int row = blockIdx.x;
  const int tid = threadIdx.x;
  float* s = src + (size_t)row * D_;
  const float* a = add + (size_t)row * D_;
  float x[4];
  float sum = 0.f, sq = 0.f;
#pragma unroll
  for (int i = 0; i < 4; ++i) {
    const int d = tid + i * 256;
    const float v = s[d] + a[d];
    x[i] = v; sum += v; sq += v * v;
  }
#pragma unroll
  for (int off = 32; off >= 1; off >>= 1) { sum += __shfl_xor(sum, off); sq += __shfl_xor(sq, off); }
  __shared__ float red[8];
  const int wid = tid >> 6;
  if ((tid & 63) == 0) { red[wid] = sum; red[4 + wid] = sq; }
  __syncthreads();
  sum = red[0] + red[1] + red[2] + red[3];
  sq = red[4] + red[5] + red[6] + red[7];
  const float mean = sum * (1.f / 1024.f);
  const float var = sq * (1.f / 1024.f) - mean * mean;
  const float rstd = rsqrtf(var + 1e-5f);
#pragma unroll
  for (int i = 0; i < 4; ++i) {
    const int d = tid + i * 256;
    const float y = (x[i] - mean) * rstd * g[d] + bb[d];
    s[d] = y;
    outb[(size_t)row * D_ + d] = f2bf(y);
  }
}

// ---------------------------------------------------------------------------
// Host orchestration
// ---------------------------------------------------------------------------
static inline int cdiv(int a, int b) { return (a + b - 1) / b; }

extern "C" void kernel_launch(void* const* d_in, const int* in_sizes, int n_in,
                              void* d_out, int out_size, void* d_ws, size_t ws_size,
                              hipStream_t stream) {
  const float* x    = (const float*)d_in[0];
  const float* Wq   = (const float*)d_in[1];
  const float* Wk   = (const float*)d_in[2];
  const float* Wv   = (const float*)d_in[3];
  const float* Wpk  = (const float*)d_in[4];
  const float* bpk  = (const float*)d_in[5];
  const float* Wpv  = (const float*)d_in[6];
  const float* bpv  = (const float*)d_in[7];
  const float* g1   = (const float*)d_in[8];
  const float* b1ln = (const float*)d_in[9];
  const float* W1   = (const float*)d_in[10];
  const float* b1   = (const float*)d_in[11];
  const float* W2   = (const float*)d_in[12];
  const float* b2   = (const float*)d_in[13];
  const float* g2   = (const float*)d_in[14];
  const float* b2ln = (const float*)d_in[15];

  char* wsb = (char*)d_ws;
  float* cosT = (float*)(wsb + 0);                //   256 KB
  float* sinT = (float*)(wsb + 262144);           //   256 KB
  float* srcf = (float*)(wsb + 524288);           // 32.77 MB fp32 residual
  u16* srcb   = (u16*)(wsb + 33292288);           // 16.38 MB bf16 mirror
  u16* QKVb   = (u16*)(wsb + 49676288);           // 49.15 MB [8000][3072]
  u16* Ttmp   = (u16*)(wsb + 98828288);           // 16.78 MB [8][1024][1024]
  u16* Km     = (u16*)(wsb + 115605504);          // 16.38 MB [8][1000][1024]
  u16* Vmt    = (u16*)(wsb + 131989504);          // 16.78 MB [8][1024 d][1024 keys]
  u16* wbuf   = (u16*)(wsb + 148766720);          // 27.07 MB layer weights
  u16* hB     = QKVb;  // [8000][4096] overlaps QKVb+Ttmp (dead at FFN time)

  u16* wqB  = wbuf + 0;          // [3072][1024] fused q,k,v
  u16* wpkB = wbuf + 3145728;    // [1000][1000]
  u16* wpvB = wbuf + 4145728;
  u16* w1B  = wbuf + 5145728;    // [4096][1024]
  u16* w2B  = wbuf + 9340032;    // [1024][4096]

  float* yF = (float*)d_out;

  tab_kernel<<<250, 256, 0, stream>>>(cosT, sinT);
  hipMemcpyAsync(srcf, x, (size_t)BT_ * D_ * sizeof(float), hipMemcpyDeviceToDevice, stream);
  convert_kernel<<<cdiv(BT_ * D_, 1024), 256, 0, stream>>>(x, srcb, BT_ * D_);

  for (int l = 0; l < 4; ++l) {
    convert_kernel<<<cdiv(1048576, 1024), 256, 0, stream>>>(Wq + (size_t)l * 1048576, wqB, 1048576);
    convert_kernel<<<cdiv(1048576, 1024), 256, 0, stream>>>(Wk + (size_t)l * 1048576, wqB + 1048576, 1048576);
    convert_kernel<<<cdiv(1048576, 1024), 256, 0, stream>>>(Wv + (size_t)l * 1048576, wqB + 2097152, 1048576);
    convert_kernel<<<cdiv(1000000, 1024), 256, 0, stream>>>(Wpk + (size_t)l * 1000000, wpkB, 1000000);
    convert_kernel<<<cdiv(1000000, 1024), 256, 0, stream>>>(Wpv + (size_t)l * 1000000, wpvB, 1000000);
    convert_kernel<<<cdiv(4194304, 1024), 256, 0, stream>>>(W1 + (size_t)l * 4194304, w1B, 4194304);
    convert_kernel<<<cdiv(4194304, 1024), 256, 0, stream>>>(W2 + (size_t)l * 4194304, w2B, 4194304);

    // Fused QKV: (8000x3072) = srcb x [Wq;Wk;Wv]^T   [fine-phase 256x256]
    gemm8p<0, false, true><<<dim3(12, 32), 512, 0, stream>>>(
        srcb, wqB, QKVb, nullptr, BT_, 3072, 1024, 1024, 1024, 3072);

    // K position-mix via transpose + NT GEMM
    transpose_kernel<<<dim3(16, 16, 8), 256, 0, stream>>>(QKVb, Ttmp, 1024);
    gemm_nt<1, false, true><<<dim3(8, 8, 8), 256, 0, stream>>>(
        wpkB, Ttmp, Km, bpk + (size_t)l * 1000, 1000, 1024, 1024,
        1000, 1024, 1024, 0L, 1048576L, 1024000L);

    // V position-mix (transposed output)
    transpose_kernel<<<dim3(16, 16, 8), 256, 0, stream>>>(QKVb, Ttmp, 2048);
    gemm_nt<2, false, true><<<dim3(8, 8, 8), 256, 0, stream>>>(
        Ttmp, wpvB, Vmt, bpv + (size_t)l * 1000, 1024, 1000, 1024,
        1024, 1000, 1024, 1048576L, 0L, 1048576L);

    rope_kernel<<<16000, 256, 0, stream>>>(QKVb, 3072, cosT, sinT);  // Q
    rope_kernel<<<16000, 256, 0, stream>>>(Km, 1024, cosT, sinT);

    attn_kernel<<<dim3(8, 64), 256, 0, stream>>>(QKVb, 3072, Km, Vmt, yF);

    addln_kernel<<<BT_, 256, 0, stream>>>(srcf, yF, g1 + (size_t)l * 1024,
                                          b1ln + (size_t)l * 1024, srcb);

    // FFN1 (+bias+gelu) -> bf16 h   [fine-phase 256x256]
    gemm8p<2, true, true><<<dim3(16, 32), 512, 0, stream>>>(
        srcb, w1B, hB, b1 + (size_t)l * 4096, BT_, 4096, 1024, 1024, 1024, 4096);
    // FFN2 (+bias) -> fp32 d_out    [m97 structure, 504 blocks]
    gemm_nt<2, false, false><<<dim3(8, 63), 256, 0, stream>>>(
        hB, w2B, d_out, b2 + (size_t)l * 1024, BT_, 1024, 4096, 4096, 4096, 1024, 0, 0, 0);

    addln_kernel<<<BT_, 256, 0, stream>>>(srcf, yF, g2 + (size_t)l * 1024,
                                          b2ln + (size_t)l * 1024, srcb);
  }

  hipMemcpyAsync(d_out, srcf, (size_t)BT_ * D_ * sizeof(float), hipMemcpyDeviceToDevice, stream);
}

// Round 6
// 2285.890 us; speedup vs baseline: 1.1999x; 1.1302x over previous
//
#include <hip/hip_runtime.h>
#include <cstdint>
#include <cstddef>

// ---------------------------------------------------------------------------
// SelfAttentionTransformer on MI355X (gfx950).
// L=4, D=1024, H=8, HS=128, T=1000, DFF=4096, B=8.
// R5: single GEMM kernel "gemm2p" = m97 structure (128x128, BK=32, 256 thr)
//     + double-buffered LDS with STAGE-before-compute (guide's minimum
//     2-phase), + proven LDS swizzle (0 conflicts), + setprio.
// ---------------------------------------------------------------------------

typedef unsigned short u16;
typedef unsigned int u32;
typedef __attribute__((ext_vector_type(8))) short s16x8;   // 8 bf16 raw bits
typedef __attribute__((ext_vector_type(4))) float f32x4;

#define DEV static __device__ __forceinline__

DEV float bf2f(u16 u) { union { u32 u; float f; } v; v.u = ((u32)u) << 16; return v.f; }
DEV u16 f2bf(float f) {
  union { float f; u32 u; } v; v.f = f;
  return (u16)((v.u + 0x7fffu + ((v.u >> 16) & 1u)) >> 16);   // RNE
}

#define MFMA(acc_, a_, b_) \
  asm volatile("v_mfma_f32_16x16x32_bf16 %0, %1, %2, %0" : "+v"(acc_) : "v"(a_), "v"(b_))

#define GLD16(g_, l_) \
  __builtin_amdgcn_global_load_lds((const __attribute__((address_space(1))) void*)(g_), \
                                   (__attribute__((address_space(3))) void*)(l_), 16, 0, 0)

static constexpr int T_ = 1000, D_ = 1024, H_ = 8, HS_ = 128, B_ = 8;
static constexpr int BT_ = B_ * T_;   // 8000

// ---------------------------------------------------------------------------
__global__ void tab_kernel(float* __restrict__ ct, float* __restrict__ st) {
  const int id = blockIdx.x * 256 + threadIdx.x;   // 64000
  const int i = id & 63, t = id >> 6;
  const float theta = powf(10000.f, -(float)i * (1.f / 64.f));
  const float ang = (float)t * theta;
  ct[id] = cosf(ang);
  st[id] = sinf(ang);
}

__global__ void convert_kernel(const float* __restrict__ in, u16* __restrict__ out, int n) {
  const int i = (blockIdx.x * 256 + threadIdx.x) * 4;
  if (i < n) {
    const float4 v = *(const float4*)(in + i);
    uint2 pk;
    pk.x = (u32)f2bf(v.x) | ((u32)f2bf(v.y) << 16);
    pk.y = (u32)f2bf(v.z) | ((u32)f2bf(v.w) << 16);
    *(uint2*)(out + i) = pk;
  }
}

// ---------------------------------------------------------------------------
// Transpose a (t,d) slice of QKVb into out[b][d][t], t zero-padded to 1024.
// ---------------------------------------------------------------------------
__global__ __launch_bounds__(256) void transpose_kernel(const u16* __restrict__ in,
                                                        u16* __restrict__ out, int cb) {
  __shared__ u16 tile[64][72];
  const int tt = blockIdx.x, dt = blockIdx.y, b = blockIdx.z;
  const int tid = threadIdx.x;
  const int r = tid >> 2, cq = (tid & 3) << 4;
  const int t = tt * 64 + r;
#pragma unroll
  for (int v = 0; v < 2; ++v) {
    s16x8 val = {};
    if (t < T_) val = *(const s16x8*)(in + (size_t)(b * 1000 + t) * 3072 + cb + dt * 64 + cq + v * 8);
    *(s16x8*)&tile[r][cq + v * 8] = val;
  }
  __syncthreads();
  const int d = dt * 64 + r;
  u16 vals[16];
#pragma unroll
  for (int j = 0; j < 16; ++j) vals[j] = tile[cq + j][r];
  u16* o = out + (size_t)b * 1048576 + (size_t)d * 1024 + tt * 64 + cq;
  *(s16x8*)o = *(s16x8*)&vals[0];
  *(s16x8*)(o + 8) = *(s16x8*)&vals[8];
}

// ---------------------------------------------------------------------------
// 2-phase NT GEMM: C[m,n] = sum_k A[m,k]*B[n,k] (+bias/gelu).
// 128x128 tile, BK=32, 256 threads (4 waves 2x2), double-buffered LDS.
// Per K-tile: issue next-tile global_load_lds FIRST, then ds_read+MFMA on
// current buffer, then one __syncthreads (vmcnt drain overlaps compute).
// LDS swizzle: 16B granule ^= (row>>1)&3 — inverse-applied on global source
// (linear LDS dest per rule #21), same XOR on the ds_read side.
// Requires K % 32 == 0 (zero-pad B if shorter). M/N tails via clamp+guard.
// ---------------------------------------------------------------------------
template <int BIAS, bool ACT, bool OUTBF>   // BIAS: 0 none, 1 row, 2 col
__global__ __launch_bounds__(256) void gemm2p(
    const u16* __restrict__ A, const u16* __restrict__ B, void* __restrict__ Cv,
    const float* __restrict__ bias, int M, int N, int K, int lda, int ldb, int ldc,
    long sA, long sB, long sC) {
  __shared__ alignas(16) u16 As[2][4096];
  __shared__ alignas(16) u16 Bs[2][4096];
  const int z = blockIdx.z;
  A += (size_t)z * (size_t)sA;
  B += (size_t)z * (size_t)sB;
  const int m0 = blockIdx.y * 128, n0 = blockIdx.x * 128;
  const int tid = threadIdx.x;
  const int wid = tid >> 6, lane = tid & 63;
  const int wr = wid >> 1, wc = wid & 1;
  const int l15 = lane & 15, l4 = lane >> 4;
  // Staging: row = tid>>2 (within 64-row half), granule pre-swizzled.
  const int srow = tid >> 2;
  const int sg = ((tid & 3) ^ ((tid >> 3) & 3)) << 3;
  const u16* gA0 = A + (size_t)min(m0 + srow, M - 1) * lda + sg;
  const u16* gA1 = A + (size_t)min(m0 + 64 + srow, M - 1) * lda + sg;
  const u16* gB0 = B + (size_t)min(n0 + srow, N - 1) * ldb + sg;
  const u16* gB1 = B + (size_t)min(n0 + 64 + srow, N - 1) * ldb + sg;
  // Fragment read offsets (swizzle XOR on the 16B granule; row bits 1..2 = l15>>1).
  const int gg = (l4 ^ ((l15 >> 1) & 3)) << 3;
  const int aBase = (wr * 64 + l15) * 32 + gg;
  const int bBase = (wc * 64 + l15) * 32 + gg;

  f32x4 acc[4][4] = {};
  const int KT = K >> 5;
  // Prologue: stage tile 0 into buf 0.
  GLD16(gA0, &As[0][tid * 8]);
  GLD16(gA1, &As[0][(256 + tid) * 8]);
  GLD16(gB0, &Bs[0][tid * 8]);
  GLD16(gB1, &Bs[0][(256 + tid) * 8]);
  __syncthreads();
  int cur = 0;
#pragma unroll 1
  for (int kt = 0; kt < KT; ++kt) {
    if (kt + 1 < KT) {   // issue next-tile loads BEFORE compute (they overlap)
      const int kb = (kt + 1) << 5;
      GLD16(gA0 + kb, &As[cur ^ 1][tid * 8]);
      GLD16(gA1 + kb, &As[cur ^ 1][(256 + tid) * 8]);
      GLD16(gB0 + kb, &Bs[cur ^ 1][tid * 8]);
      GLD16(gB1 + kb, &Bs[cur ^ 1][(256 + tid) * 8]);
    }
    s16x8 af[4], bfr[4];
#pragma unroll
    for (int i = 0; i < 4; ++i) af[i] = *(const s16x8*)&As[cur][aBase + i * 512];
#pragma unroll
    for (int i = 0; i < 4; ++i) bfr[i] = *(const s16x8*)&Bs[cur][bBase + i * 512];
    __builtin_amdgcn_s_setprio(1);
#pragma unroll
    for (int mi = 0; mi < 4; ++mi)
#pragma unroll
      for (int ni = 0; ni < 4; ++ni) MFMA(acc[mi][ni], af[mi], bfr[ni]);
    __builtin_amdgcn_s_setprio(0);
    __syncthreads();   // drains vmcnt: next buffer resident; reads of cur done
    cur ^= 1;
  }
  asm volatile("s_nop 7\n\ts_nop 7"
               : "+v"(acc[3][0]), "+v"(acc[3][1]), "+v"(acc[3][2]), "+v"(acc[3][3]));
#pragma unroll
  for (int mi = 0; mi < 4; ++mi) {
#pragma unroll
    for (int ni = 0; ni < 4; ++ni) {
      const int colg = n0 + wc * 64 + ni * 16 + l15;
#pragma unroll
      for (int r = 0; r < 4; ++r) {
        const int rowg = m0 + wr * 64 + mi * 16 + l4 * 4 + r;
        if (rowg < M && colg < N) {
          float v = acc[mi][ni][r];
          if (BIAS == 1) v += bias[rowg];
          if (BIAS == 2) v += bias[colg];
          if (ACT) v = 0.5f * v * (1.0f + erff(v * 0.70710678118654752f));
          const size_t idx = (size_t)z * (size_t)sC + (size_t)rowg * ldc + colg;
          if (OUTBF) ((u16*)Cv)[idx] = f2bf(v);
          else       ((float*)Cv)[idx] = v;
        }
      }
    }
  }
}

// ---------------------------------------------------------------------------
// RoPE in place, row stride ld.
// ---------------------------------------------------------------------------
__global__ __launch_bounds__(256) void rope_kernel(u16* __restrict__ X, int ld,
                                                   const float* __restrict__ ct,
                                                   const float* __restrict__ st) {
  const int id = blockIdx.x * 256 + threadIdx.x;  // 4,096,000
  const int i = id & 63;
  const int h = (id >> 6) & 7;
  const int bt = id >> 9;
  const int t = bt % 1000;
  const size_t base = (size_t)bt * ld + h * HS_ + i * 2;
  u32* p = (u32*)(X + base);
  const u32 w = *p;
  const float xr = bf2f((u16)(w & 0xffffu));
  const float xi = bf2f((u16)(w >> 16));
  const float c = ct[t * 64 + i], s = st[t * 64 + i];
  const float outr = xr * c - xi * s;
  const float outi = xr * s + xi * c;
  *p = (u32)f2bf(outr) | ((u32)f2bf(outi) << 16);
}

// ---------------------------------------------------------------------------
// Flash attention (non-causal), QBLK=128 (4 waves x 32 q-rows), KVBLK=64.
// ---------------------------------------------------------------------------
__global__ __launch_bounds__(256) void attn_kernel(const u16* __restrict__ Q, int ldq,
                                                   const u16* __restrict__ Km,
                                                   const u16* __restrict__ Vmt,
                                                   float* __restrict__ Y) {
  __shared__ alignas(16) u16 Ks[64][136];
  __shared__ alignas(16) u16 Vts[128][72];
  __shared__ alignas(16) u16 Ps[4][32][72];
  const int qt = blockIdx.x;
  const int bh = blockIdx.y;
  const int b = bh >> 3, h = bh & 7;
  const int tid = threadIdx.x;
  const int w = tid >> 6, lane = tid & 63;
  const int l15 = lane & 15, l4 = lane >> 4;
  const size_t qbase = (size_t)b * 1000 * ldq + h * HS_;
  const size_t kbase = (size_t)b * 1024000 + h * HS_;
  const size_t vbase = (size_t)b * 1048576 + (size_t)(h * HS_) * 1024;
  const int q0 = qt * 128 + w * 32;
  s16x8 aq[2][4];
#pragma unroll
  for (int qf = 0; qf < 2; ++qf) {
    const int qrow = q0 + qf * 16 + l15;
#pragma unroll
    for (int c = 0; c < 4; ++c) {
      s16x8 v = {};
      if (qrow < T_) v = *(const s16x8*)(Q + qbase + (size_t)qrow * ldq + c * 32 + l4 * 8);
      aq[qf][c] = v;
    }
  }
  f32x4 acc[2][8] = {};
  float m_run[2][4], l_run[2][4];
#pragma unroll
  for (int qf = 0; qf < 2; ++qf)
#pragma unroll
    for (int r = 0; r < 4; ++r) { m_run[qf][r] = -1e30f; l_run[qf][r] = 0.f; }
  const float SCALE = 0.08838834764831845f;
  for (int kt = 0; kt < 16; ++kt) {
    {
      const int r = tid >> 2, c0 = (tid & 3) << 5;
      const int kk = kt * 64 + r;
#pragma unroll
      for (int v = 0; v < 4; ++v) {
        s16x8 val = {};
        if (kk < T_) val = *(const s16x8*)(Km + kbase + (size_t)kk * 1024 + c0 + v * 8);
        *(s16x8*)&Ks[r][c0 + v * 8] = val;
      }
      const int r2 = tid >> 1, c2s = (tid & 1) << 5;
#pragma unroll
      for (int v = 0; v < 4; ++v) {
        const s16x8 val = *(const s16x8*)(Vmt + vbase + (size_t)r2 * 1024 + kt * 64 + c2s + v * 8);
        *(s16x8*)&Vts[r2][c2s + v * 8] = val;
      }
    }
    __syncthreads();
    f32x4 sacc[2][4] = {};
#pragma unroll
    for (int c = 0; c < 4; ++c) {
      s16x8 bk[4];
#pragma unroll
      for (int f = 0; f < 4; ++f) bk[f] = *(const s16x8*)&Ks[f * 16 + l15][c * 32 + l4 * 8];
#pragma unroll
      for (int qf = 0; qf < 2; ++qf)
#pragma unroll
        for (int f = 0; f < 4; ++f) MFMA(sacc[qf][f], aq[qf][c], bk[f]);
    }
    asm volatile("s_nop 7\n\ts_nop 7"
                 : "+v"(sacc[0][0]), "+v"(sacc[0][1]), "+v"(sacc[0][2]), "+v"(sacc[0][3]),
                   "+v"(sacc[1][0]), "+v"(sacc[1][1]), "+v"(sacc[1][2]), "+v"(sacc[1][3]));
#pragma unroll
    for (int qf = 0; qf < 2; ++qf) {
      float sv[4][4];
#pragma unroll
      for (int f = 0; f < 4; ++f) {
        const int key = kt * 64 + f * 16 + l15;
#pragma unroll
        for (int r = 0; r < 4; ++r) sv[f][r] = (key < T_) ? sacc[qf][f][r] * SCALE : -1e30f;
      }
#pragma unroll
      for (int r = 0; r < 4; ++r) {
        float mx = fmaxf(fmaxf(sv[0][r], sv[1][r]), fmaxf(sv[2][r], sv[3][r]));
#pragma unroll
        for (int off = 8; off >= 1; off >>= 1) mx = fmaxf(mx, __shfl_xor(mx, off));
        const float mn = fmaxf(m_run[qf][r], mx);
        const float corr = __expf(m_run[qf][r] - mn);
        m_run[qf][r] = mn;
        float rs = 0.f;
#pragma unroll
        for (int f = 0; f < 4; ++f) {
          const float p = __expf(sv[f][r] - mn);
          rs += p;
          Ps[w][qf * 16 + l4 * 4 + r][f * 16 + l15] = f2bf(p);
        }
#pragma unroll
        for (int off = 8; off >= 1; off >>= 1) rs += __shfl_xor(rs, off);
        l_run[qf][r] = l_run[qf][r] * corr + rs;
#pragma unroll
        for (int n = 0; n < 8; ++n) acc[qf][n][r] *= corr;
      }
    }
    asm volatile("s_waitcnt lgkmcnt(0)" ::: "memory");
#pragma unroll
    for (int c2 = 0; c2 < 2; ++c2) {
      s16x8 pa[2];
#pragma unroll
      for (int qf = 0; qf < 2; ++qf)
        pa[qf] = *(const s16x8*)&Ps[w][qf * 16 + l15][c2 * 32 + l4 * 8];
#pragma unroll
      for (int n = 0; n < 8; ++n) {
        const s16x8 vb = *(const s16x8*)&Vts[n * 16 + l15][c2 * 32 + l4 * 8];
#pragma unroll
        for (int qf = 0; qf < 2; ++qf) MFMA(acc[qf][n], pa[qf], vb);
      }
    }
    __syncthreads();
  }
  asm volatile("s_nop 7\n\ts_nop 7"
               : "+v"(acc[0][6]), "+v"(acc[0][7]), "+v"(acc[1][6]), "+v"(acc[1][7]));
#pragma unroll
  for (int qf = 0; qf < 2; ++qf)
#pragma unroll
    for (int n = 0; n < 8; ++n)
#pragma unroll
      for (int r = 0; r < 4; ++r) {
        const int q = q0 + qf * 16 + l4 * 4 + r;
        if (q < T_)
          Y[(size_t)(b * 1000 + q) * 1024 + h * HS_ + n * 16 + l15] = acc[qf][n][r] / l_run[qf][r];
      }
}

// ---------------------------------------------------------------------------
// src = LN(src + add) * g + b  (fp32 master) + bf16 mirror.
// ---------------------------------------------------------------------------
__global__ __launch_bounds__(256) void addln_kernel(float* __restrict__ src,
                                                    const float* __restrict__ add,
                                                    const float* __restrict__ g,
                                                    const float* __restrict__ bb,
                                                    u16* __restrict__ outb) {
  const int row = blockIdx.x;
  const int tid = threadIdx.x;
  float* s = src + (size_t)row * D_;
  const float* a = add + (size_t)row * D_;
  float x[4];
  float sum = 0.f, sq = 0.f;
#pragma unroll
  for (int i = 0; i < 4; ++i) {
    const int d = tid + i * 256;
    const float v = s[d] + a[d];
    x[i] = v; sum += v; sq += v * v;
  }
#pragma unroll
  for (int off = 32; off >= 1; off >>= 1) { sum += __shfl_xor(sum, off); sq += __shfl_xor(sq, off); }
  __shared__ float red[8];
  const int wid = tid >> 6;
  if ((tid & 63) == 0) { red[wid] = sum; red[4 + wid] = sq; }
  __syncthreads();
  sum = red[0] + red[1] + red[2] + red[3];
  sq = red[4] + red[5] + red[6] + red[7];
  const float mean = sum * (1.f / 1024.f);
  const float var = sq * (1.f / 1024.f) - mean * mean;
  const float rstd = rsqrtf(var + 1e-5f);
#pragma unroll
  for (int i = 0; i < 4; ++i) {
    const int d = tid + i * 256;
    const float y = (x[i] - mean) * rstd * g[d] + bb[d];
    s[d] = y;
    outb[(size_t)row * D_ + d] = f2bf(y);
  }
}

// ---------------------------------------------------------------------------
// Host orchestration
// ---------------------------------------------------------------------------
static inline int cdiv(int a, int b) { return (a + b - 1) / b; }

extern "C" void kernel_launch(void* const* d_in, const int* in_sizes, int n_in,
                              void* d_out, int out_size, void* d_ws, size_t ws_size,
                              hipStream_t stream) {
  const float* x    = (const float*)d_in[0];
  const float* Wq   = (const float*)d_in[1];
  const float* Wk   = (const float*)d_in[2];
  const float* Wv   = (const float*)d_in[3];
  const float* Wpk  = (const float*)d_in[4];
  const float* bpk  = (const float*)d_in[5];
  const float* Wpv  = (const float*)d_in[6];
  const float* bpv  = (const float*)d_in[7];
  const float* g1   = (const float*)d_in[8];
  const float* b1ln = (const float*)d_in[9];
  const float* W1   = (const float*)d_in[10];
  const float* b1   = (const float*)d_in[11];
  const float* W2   = (const float*)d_in[12];
  const float* b2   = (const float*)d_in[13];
  const float* g2   = (const float*)d_in[14];
  const float* b2ln = (const float*)d_in[15];

  char* wsb = (char*)d_ws;
  float* cosT = (float*)(wsb + 0);                //   256 KB
  float* sinT = (float*)(wsb + 262144);           //   256 KB
  float* srcf = (float*)(wsb + 524288);           // 32.77 MB fp32 residual
  u16* srcb   = (u16*)(wsb + 33292288);           // 16.38 MB bf16 mirror
  u16* QKVb   = (u16*)(wsb + 49676288);           // 49.15 MB [8000][3072]
  u16* Ttmp   = (u16*)(wsb + 98828288);           // 16.78 MB [8][1024][1024]
  u16* Km     = (u16*)(wsb + 115605504);          // 16.38 MB [8][1000][1024]
  u16* Vmt    = (u16*)(wsb + 131989504);          // 16.78 MB [8][1024 d][1024 keys]
  u16* wbuf   = (u16*)(wsb + 148766720);          // 27.07 MB layer weights
  u16* hB     = QKVb;  // [8000][4096] overlaps QKVb+Ttmp (dead at FFN time)

  u16* wqB  = wbuf + 0;          // [3072][1024] fused q,k,v
  u16* wpkB = wbuf + 3145728;    // [1000][1000]
  u16* wpvB = wbuf + 4145728;
  u16* w1B  = wbuf + 5145728;    // [4096][1024]
  u16* w2B  = wbuf + 9340032;    // [1024][4096]

  float* yF = (float*)d_out;

  tab_kernel<<<250, 256, 0, stream>>>(cosT, sinT);
  hipMemcpyAsync(srcf, x, (size_t)BT_ * D_ * sizeof(float), hipMemcpyDeviceToDevice, stream);
  convert_kernel<<<cdiv(BT_ * D_, 1024), 256, 0, stream>>>(x, srcb, BT_ * D_);

  for (int l = 0; l < 4; ++l) {
    convert_kernel<<<cdiv(1048576, 1024), 256, 0, stream>>>(Wq + (size_t)l * 1048576, wqB, 1048576);
    convert_kernel<<<cdiv(1048576, 1024), 256, 0, stream>>>(Wk + (size_t)l * 1048576, wqB + 1048576, 1048576);
    convert_kernel<<<cdiv(1048576, 1024), 256, 0, stream>>>(Wv + (size_t)l * 1048576, wqB + 2097152, 1048576);
    convert_kernel<<<cdiv(1000000, 1024), 256, 0, stream>>>(Wpk + (size_t)l * 1000000, wpkB, 1000000);
    convert_kernel<<<cdiv(1000000, 1024), 256, 0, stream>>>(Wpv + (size_t)l * 1000000, wpvB, 1000000);
    convert_kernel<<<cdiv(4194304, 1024), 256, 0, stream>>>(W1 + (size_t)l * 4194304, w1B, 4194304);
    convert_kernel<<<cdiv(4194304, 1024), 256, 0, stream>>>(W2 + (size_t)l * 4194304, w2B, 4194304);

    // Fused QKV: (8000x3072) = srcb x [Wq;Wk;Wv]^T
    gemm2p<0, false, true><<<dim3(24, 63, 1), 256, 0, stream>>>(
        srcb, wqB, QKVb, nullptr, BT_, 3072, 1024, 1024, 1024, 3072, 0, 0, 0);

    // K position-mix via transpose + NT GEMM
    transpose_kernel<<<dim3(16, 16, 8), 256, 0, stream>>>(QKVb, Ttmp, 1024);
    gemm2p<1, false, true><<<dim3(8, 8, 8), 256, 0, stream>>>(
        wpkB, Ttmp, Km, bpk + (size_t)l * 1000, 1000, 1024, 1024,
        1000, 1024, 1024, 0L, 1048576L, 1024000L);

    // V position-mix (transposed output)
    transpose_kernel<<<dim3(16, 16, 8), 256, 0, stream>>>(QKVb, Ttmp, 2048);
    gemm2p<2, false, true><<<dim3(8, 8, 8), 256, 0, stream>>>(
        Ttmp, wpvB, Vmt, bpv + (size_t)l * 1000, 1024, 1000, 1024,
        1024, 1000, 1024, 1048576L, 0L, 1048576L);

    rope_kernel<<<16000, 256, 0, stream>>>(QKVb, 3072, cosT, sinT);  // Q
    rope_kernel<<<16000, 256, 0, stream>>>(Km, 1024, cosT, sinT);

    attn_kernel<<<dim3(8, 64), 256, 0, stream>>>(QKVb, 3072, Km, Vmt, yF);

    addln_kernel<<<BT_, 256, 0, stream>>>(srcf, yF, g1 + (size_t)l * 1024,
                                          b1ln + (size_t)l * 1024, srcb);

    // FFN1 (+bias+gelu) -> bf16 h
    gemm2p<2, true, true><<<dim3(32, 63, 1), 256, 0, stream>>>(
        srcb, w1B, hB, b1 + (size_t)l * 4096, BT_, 4096, 1024, 1024, 1024, 4096, 0, 0, 0);
    // FFN2 (+bias) -> fp32 d_out
    gemm2p<2, false, false><<<dim3(8, 63, 1), 256, 0, stream>>>(
        hB, w2B, d_out, b2 + (size_t)l * 1024, BT_, 1024, 4096, 4096, 4096, 1024, 0, 0, 0);

    addln_kernel<<<BT_, 256, 0, stream>>>(srcf, yF, g2 + (size_t)l * 1024,
                                          b2ln + (size_t)l * 1024, srcb);
  }

  hipMemcpyAsync(d_out, srcf, (size_t)BT_ * D_ * sizeof(float), hipMemcpyDeviceToDevice, stream);
}

// Round 7
// 2205.236 us; speedup vs baseline: 1.2437x; 1.0366x over previous
//
#include <hip/hip_runtime.h>
#include <cstdint>
#include <cstddef>

// ---------------------------------------------------------------------------
// SelfAttentionTransformer on MI355X (gfx950).
// L=4, D=1024, H=8, HS=128, T=1000, DFF=4096, B=8.
// R6: fuse data motion — QKV epilogue emits K^T/V^T directly (no transpose
//     kernels), RoPE fused into attention load/staging (no rope kernels),
//     bf16 attention/FFN2 outputs + vectorized addln. GEMM = R5's gemm2p.
// ---------------------------------------------------------------------------

typedef unsigned short u16;
typedef unsigned int u32;
typedef __attribute__((ext_vector_type(8))) short s16x8;   // 8 bf16 raw bits
typedef __attribute__((ext_vector_type(4))) float f32x4;
typedef __attribute__((ext_vector_type(4))) unsigned short u16x4;

#define DEV static __device__ __forceinline__

DEV float bf2f(u16 u) { union { u32 u; float f; } v; v.u = ((u32)u) << 16; return v.f; }
DEV u16 f2bf(float f) {
  union { float f; u32 u; } v; v.f = f;
  return (u16)((v.u + 0x7fffu + ((v.u >> 16) & 1u)) >> 16);   // RNE
}

#define MFMA(acc_, a_, b_) \
  asm volatile("v_mfma_f32_16x16x32_bf16 %0, %1, %2, %0" : "+v"(acc_) : "v"(a_), "v"(b_))

#define GLD16(g_, l_) \
  __builtin_amdgcn_global_load_lds((const __attribute__((address_space(1))) void*)(g_), \
                                   (__attribute__((address_space(3))) void*)(l_), 16, 0, 0)

static constexpr int T_ = 1000, D_ = 1024, H_ = 8, HS_ = 128, B_ = 8;
static constexpr int BT_ = B_ * T_;   // 8000

// rope on 8 packed bf16 (4 pairs), table base i0 (pair index of element 0).
DEV void rope8(s16x8& v, const float* __restrict__ ct, const float* __restrict__ st,
               int t, int i0) {
  const f32x4 c4 = *(const f32x4*)(ct + t * 64 + i0);
  const f32x4 s4 = *(const f32x4*)(st + t * 64 + i0);
#pragma unroll
  for (int p = 0; p < 4; ++p) {
    const float xr = bf2f((u16)v[2 * p]), xi = bf2f((u16)v[2 * p + 1]);
    v[2 * p]     = (short)f2bf(xr * c4[p] - xi * s4[p]);
    v[2 * p + 1] = (short)f2bf(xr * s4[p] + xi * c4[p]);
  }
}

// ---------------------------------------------------------------------------
__global__ void tab_kernel(float* __restrict__ ct, float* __restrict__ st) {
  const int id = blockIdx.x * 256 + threadIdx.x;   // 64000
  const int i = id & 63, t = id >> 6;
  const float theta = powf(10000.f, -(float)i * (1.f / 64.f));
  const float ang = (float)t * theta;
  ct[id] = cosf(ang);
  st[id] = sinf(ang);
}

__global__ void convert_kernel(const float* __restrict__ in, u16* __restrict__ out, int n) {
  const int i = (blockIdx.x * 256 + threadIdx.x) * 4;
  if (i < n) {
    const float4 v = *(const float4*)(in + i);
    uint2 pk;
    pk.x = (u32)f2bf(v.x) | ((u32)f2bf(v.y) << 16);
    pk.y = (u32)f2bf(v.z) | ((u32)f2bf(v.w) << 16);
    *(uint2*)(out + i) = pk;
  }
}

// Zero the t/u in [1000,1024) tails of KTg, VTg, Vmt ([8][1024][1024] each).
__global__ void zerotail_kernel(u16* __restrict__ KTg, u16* __restrict__ VTg,
                                u16* __restrict__ Vmt) {
  const int id = blockIdx.x * 256 + threadIdx.x;   // 3 * 8192 * 24 = 589824
  if (id >= 3 * 8192 * 24) return;
  const int which = id / 196608, rem = id % 196608;
  const int bd = rem / 24, t = 1000 + rem % 24;
  u16* p = (which == 0) ? KTg : (which == 1) ? VTg : Vmt;
  p[(size_t)bd * 1024 + t] = 0;
}

// ---------------------------------------------------------------------------
// 2-phase NT GEMM: C[m,n] = sum_k A[m,k]*B[n,k] (+bias/gelu).
// 128x128 tile, BK=32, 256 threads, double-buffered LDS, swizzled, setprio.
// SPLIT: N=3072 QKV mode — cols<1024 -> Cv (Q, ldc=1024); cols in [1024,2048)
// -> KT[b][d][t]; cols in [2048,3072) -> VT[b][d][t] (8B vector stores).
// ---------------------------------------------------------------------------
template <int BIAS, bool ACT, bool OUTBF, bool SPLIT>   // BIAS: 0 none,1 row,2 col
__global__ __launch_bounds__(256) void gemm2p(
    const u16* __restrict__ A, const u16* __restrict__ B, void* __restrict__ Cv,
    const float* __restrict__ bias, u16* __restrict__ KT, u16* __restrict__ VT,
    int M, int N, int K, int lda, int ldb, int ldc, long sA, long sB, long sC) {
  __shared__ alignas(16) u16 As[2][4096];
  __shared__ alignas(16) u16 Bs[2][4096];
  const int z = blockIdx.z;
  A += (size_t)z * (size_t)sA;
  B += (size_t)z * (size_t)sB;
  const int m0 = blockIdx.y * 128, n0 = blockIdx.x * 128;
  const int tid = threadIdx.x;
  const int wid = tid >> 6, lane = tid & 63;
  const int wr = wid >> 1, wc = wid & 1;
  const int l15 = lane & 15, l4 = lane >> 4;
  const int srow = tid >> 2;
  const int sg = ((tid & 3) ^ ((tid >> 3) & 3)) << 3;
  const u16* gA0 = A + (size_t)min(m0 + srow, M - 1) * lda + sg;
  const u16* gA1 = A + (size_t)min(m0 + 64 + srow, M - 1) * lda + sg;
  const u16* gB0 = B + (size_t)min(n0 + srow, N - 1) * ldb + sg;
  const u16* gB1 = B + (size_t)min(n0 + 64 + srow, N - 1) * ldb + sg;
  const int gg = (l4 ^ ((l15 >> 1) & 3)) << 3;
  const int aBase = (wr * 64 + l15) * 32 + gg;
  const int bBase = (wc * 64 + l15) * 32 + gg;

  f32x4 acc[4][4] = {};
  const int KT_n = K >> 5;
  GLD16(gA0, &As[0][tid * 8]);
  GLD16(gA1, &As[0][(256 + tid) * 8]);
  GLD16(gB0, &Bs[0][tid * 8]);
  GLD16(gB1, &Bs[0][(256 + tid) * 8]);
  __syncthreads();
  int cur = 0;
#pragma unroll 1
  for (int kt = 0; kt < KT_n; ++kt) {
    if (kt + 1 < KT_n) {
      const int kb = (kt + 1) << 5;
      GLD16(gA0 + kb, &As[cur ^ 1][tid * 8]);
      GLD16(gA1 + kb, &As[cur ^ 1][(256 + tid) * 8]);
      GLD16(gB0 + kb, &Bs[cur ^ 1][tid * 8]);
      GLD16(gB1 + kb, &Bs[cur ^ 1][(256 + tid) * 8]);
    }
    s16x8 af[4], bfr[4];
#pragma unroll
    for (int i = 0; i < 4; ++i) af[i] = *(const s16x8*)&As[cur][aBase + i * 512];
#pragma unroll
    for (int i = 0; i < 4; ++i) bfr[i] = *(const s16x8*)&Bs[cur][bBase + i * 512];
    __builtin_amdgcn_s_setprio(1);
#pragma unroll
    for (int mi = 0; mi < 4; ++mi)
#pragma unroll
      for (int ni = 0; ni < 4; ++ni) MFMA(acc[mi][ni], af[mi], bfr[ni]);
    __builtin_amdgcn_s_setprio(0);
    __syncthreads();
    cur ^= 1;
  }
  asm volatile("s_nop 7\n\ts_nop 7"
               : "+v"(acc[3][0]), "+v"(acc[3][1]), "+v"(acc[3][2]), "+v"(acc[3][3]));
  if constexpr (SPLIT) {
#pragma unroll
    for (int mi = 0; mi < 4; ++mi) {
      const int rb = m0 + wr * 64 + mi * 16 + l4 * 4;   // multiple of 4
      if (rb < M) {
#pragma unroll
        for (int ni = 0; ni < 4; ++ni) {
          const int colg = n0 + wc * 64 + ni * 16 + l15;
          if (colg < 1024) {
#pragma unroll
            for (int r = 0; r < 4; ++r)
              ((u16*)Cv)[(size_t)(rb + r) * 1024 + colg] = f2bf(acc[mi][ni][r]);
          } else {
            u16* dst = (colg < 2048) ? KT : VT;
            const int dcol = colg & 1023;
            const int bq = rb / 1000;
            const int tq = rb - bq * 1000;   // mult of 4, <=996: no straddle
            u16x4 pk;
#pragma unroll
            for (int r = 0; r < 4; ++r) pk[r] = f2bf(acc[mi][ni][r]);
            *(u16x4*)(dst + (size_t)bq * 1048576 + (size_t)dcol * 1024 + tq) = pk;
          }
        }
      }
    }
  } else {
#pragma unroll
    for (int mi = 0; mi < 4; ++mi) {
#pragma unroll
      for (int ni = 0; ni < 4; ++ni) {
        const int colg = n0 + wc * 64 + ni * 16 + l15;
#pragma unroll
        for (int r = 0; r < 4; ++r) {
          const int rowg = m0 + wr * 64 + mi * 16 + l4 * 4 + r;
          if (rowg < M && colg < N) {
            float v = acc[mi][ni][r];
            if (BIAS == 1) v += bias[rowg];
            if (BIAS == 2) v += bias[colg];
            if (ACT) v = 0.5f * v * (1.0f + erff(v * 0.70710678118654752f));
            const size_t idx = (size_t)z * (size_t)sC + (size_t)rowg * ldc + colg;
            if (OUTBF) ((u16*)Cv)[idx] = f2bf(v);
            else       ((float*)Cv)[idx] = v;
          }
        }
      }
    }
  }
}

// ---------------------------------------------------------------------------
// Flash attention (non-causal), QBLK=128 (4 waves x 32 q-rows), KVBLK=64.
// RoPE fused: Q at fragment load, K at LDS staging. Output bf16.
// Q: Qb[8000][1024]. Km: [b][1000][1024] (mix+bias, no rope). Vmt: [b][d][u].
// ---------------------------------------------------------------------------
__global__ __launch_bounds__(256) void attn_kernel(const u16* __restrict__ Q,
                                                   const u16* __restrict__ Km,
                                                   const u16* __restrict__ Vmt,
                                                   u16* __restrict__ Y,
                                                   const float* __restrict__ ct,
                                                   const float* __restrict__ st) {
  __shared__ alignas(16) u16 Ks[64][136];
  __shared__ alignas(16) u16 Vts[128][72];
  __shared__ alignas(16) u16 Ps[4][32][72];
  const int qt = blockIdx.x;
  const int bh = blockIdx.y;
  const int b = bh >> 3, h = bh & 7;
  const int tid = threadIdx.x;
  const int w = tid >> 6, lane = tid & 63;
  const int l15 = lane & 15, l4 = lane >> 4;
  const size_t qbase = (size_t)b * 1000 * 1024 + h * HS_;
  const size_t kbase = (size_t)b * 1024000 + h * HS_;
  const size_t vbase = (size_t)b * 1048576 + (size_t)(h * HS_) * 1024;
  const int q0 = qt * 128 + w * 32;
  s16x8 aq[2][4];
#pragma unroll
  for (int qf = 0; qf < 2; ++qf) {
    const int qrow = q0 + qf * 16 + l15;
#pragma unroll
    for (int c = 0; c < 4; ++c) {
      s16x8 v = {};
      if (qrow < T_) {
        v = *(const s16x8*)(Q + qbase + (size_t)qrow * 1024 + c * 32 + l4 * 8);
        rope8(v, ct, st, qrow, c * 16 + l4 * 4);
      }
      aq[qf][c] = v;
    }
  }
  f32x4 acc[2][8] = {};
  float m_run[2][4], l_run[2][4];
#pragma unroll
  for (int qf = 0; qf < 2; ++qf)
#pragma unroll
    for (int r = 0; r < 4; ++r) { m_run[qf][r] = -1e30f; l_run[qf][r] = 0.f; }
  const float SCALE = 0.08838834764831845f;
  for (int kt = 0; kt < 16; ++kt) {
    {
      const int r = tid >> 2, c0 = (tid & 3) << 5;
      const int kk = kt * 64 + r;
#pragma unroll
      for (int v = 0; v < 4; ++v) {
        s16x8 val = {};
        if (kk < T_) {
          val = *(const s16x8*)(Km + kbase + (size_t)kk * 1024 + c0 + v * 8);
          rope8(val, ct, st, kk, (c0 + v * 8) >> 1);   // K rope (post-mix+bias)
        }
        *(s16x8*)&Ks[r][c0 + v * 8] = val;
      }
      const int r2 = tid >> 1, c2s = (tid & 1) << 5;
#pragma unroll
      for (int v = 0; v < 4; ++v) {
        const s16x8 val = *(const s16x8*)(Vmt + vbase + (size_t)r2 * 1024 + kt * 64 + c2s + v * 8);
        *(s16x8*)&Vts[r2][c2s + v * 8] = val;
      }
    }
    __syncthreads();
    f32x4 sacc[2][4] = {};
#pragma unroll
    for (int c = 0; c < 4; ++c) {
      s16x8 bk[4];
#pragma unroll
      for (int f = 0; f < 4; ++f) bk[f] = *(const s16x8*)&Ks[f * 16 + l15][c * 32 + l4 * 8];
#pragma unroll
      for (int qf = 0; qf < 2; ++qf)
#pragma unroll
        for (int f = 0; f < 4; ++f) MFMA(sacc[qf][f], aq[qf][c], bk[f]);
    }
    asm volatile("s_nop 7\n\ts_nop 7"
                 : "+v"(sacc[0][0]), "+v"(sacc[0][1]), "+v"(sacc[0][2]), "+v"(sacc[0][3]),
                   "+v"(sacc[1][0]), "+v"(sacc[1][1]), "+v"(sacc[1][2]), "+v"(sacc[1][3]));
#pragma unroll
    for (int qf = 0; qf < 2; ++qf) {
      float sv[4][4];
#pragma unroll
      for (int f = 0; f < 4; ++f) {
        const int key = kt * 64 + f * 16 + l15;
#pragma unroll
        for (int r = 0; r < 4; ++r) sv[f][r] = (key < T_) ? sacc[qf][f][r] * SCALE : -1e30f;
      }
#pragma unroll
      for (int r = 0; r < 4; ++r) {
        float mx = fmaxf(fmaxf(sv[0][r], sv[1][r]), fmaxf(sv[2][r], sv[3][r]));
#pragma unroll
        for (int off = 8; off >= 1; off >>= 1) mx = fmaxf(mx, __shfl_xor(mx, off));
        const float mn = fmaxf(m_run[qf][r], mx);
        const float corr = __expf(m_run[qf][r] - mn);
        m_run[qf][r] = mn;
        float rs = 0.f;
#pragma unroll
        for (int f = 0; f < 4; ++f) {
          const float p = __expf(sv[f][r] - mn);
          rs += p;
          Ps[w][qf * 16 + l4 * 4 + r][f * 16 + l15] = f2bf(p);
        }
#pragma unroll
        for (int off = 8; off >= 1; off >>= 1) rs += __shfl_xor(rs, off);
        l_run[qf][r] = l_run[qf][r] * corr + rs;
#pragma unroll
        for (int n = 0; n < 8; ++n) acc[qf][n][r] *= corr;
      }
    }
    asm volatile("s_waitcnt lgkmcnt(0)" ::: "memory");
#pragma unroll
    for (int c2 = 0; c2 < 2; ++c2) {
      s16x8 pa[2];
#pragma unroll
      for (int qf = 0; qf < 2; ++qf)
        pa[qf] = *(const s16x8*)&Ps[w][qf * 16 + l15][c2 * 32 + l4 * 8];
#pragma unroll
      for (int n = 0; n < 8; ++n) {
        const s16x8 vb = *(const s16x8*)&Vts[n * 16 + l15][c2 * 32 + l4 * 8];
#pragma unroll
        for (int qf = 0; qf < 2; ++qf) MFMA(acc[qf][n], pa[qf], vb);
      }
    }
    __syncthreads();
  }
  asm volatile("s_nop 7\n\ts_nop 7"
               : "+v"(acc[0][6]), "+v"(acc[0][7]), "+v"(acc[1][6]), "+v"(acc[1][7]));
#pragma unroll
  for (int qf = 0; qf < 2; ++qf)
#pragma unroll
    for (int n = 0; n < 8; ++n)
#pragma unroll
      for (int r = 0; r < 4; ++r) {
        const int q = q0 + qf * 16 + l4 * 4 + r;
        if (q < T_)
          Y[(size_t)(b * 1000 + q) * 1024 + h * HS_ + n * 16 + l15] =
              f2bf(acc[qf][n][r] / l_run[qf][r]);
      }
}

// ---------------------------------------------------------------------------
// src = LN(src + bf16 add) * g + b  (fp32 master) + bf16 mirror. Vectorized.
// ---------------------------------------------------------------------------
__global__ __launch_bounds__(256) void addln_kernel(float* __restrict__ src,
                                                    const u16* __restrict__ add,
                                                    const float* __restrict__ g,
                                                    const float* __restrict__ bb,
                                                    u16* __restrict__ outb) {
  const int row = blockIdx.x;
  const int tid = threadIdx.x;
  const int d = tid * 4;
  float* s = src + (size_t)row * D_;
  const u16* a = add + (size_t)row * D_;
  f32x4 sv = *(const f32x4*)(s + d);
  const u16x4 av = *(const u16x4*)(a + d);
  float x[4];
  float sum = 0.f, sq = 0.f;
#pragma unroll
  for (int i = 0; i < 4; ++i) {
    const float v = sv[i] + bf2f(av[i]);
    x[i] = v; sum += v; sq += v * v;
  }
#pragma unroll
  for (int off = 32; off >= 1; off >>= 1) { sum += __shfl_xor(sum, off); sq += __shfl_xor(sq, off); }
  __shared__ float red[8];
  const int wid = tid >> 6;
  if ((tid & 63) == 0) { red[wid] = sum; red[4 + wid] = sq; }
  __syncthreads();
  sum = red[0] + red[1] + red[2] + red[3];
  sq = red[4] + red[5] + red[6] + red[7];
  const float mean = sum * (1.f / 1024.f);
  const float var = sq * (1.f / 1024.f) - mean * mean;
  const float rstd = rsqrtf(var + 1e-5f);
  const f32x4 gv = *(const f32x4*)(g + d);
  const f32x4 bv = *(const f32x4*)(bb + d);
  f32x4 yv;
  u16x4 ob;
#pragma unroll
  for (int i = 0; i < 4; ++i) {
    const float y = (x[i] - mean) * rstd * gv[i] + bv[i];
    yv[i] = y;
    ob[i] = f2bf(y);
  }
  *(f32x4*)(s + d) = yv;
  *(u16x4*)(outb + (size_t)row * D_ + d) = ob;
}

// ---------------------------------------------------------------------------
// Host orchestration
// ---------------------------------------------------------------------------
static inline int cdiv(int a, int b) { return (a + b - 1) / b; }

extern "C" void kernel_launch(void* const* d_in, const int* in_sizes, int n_in,
                              void* d_out, int out_size, void* d_ws, size_t ws_size,
                              hipStream_t stream) {
  const float* x    = (const float*)d_in[0];
  const float* Wq   = (const float*)d_in[1];
  const float* Wk   = (const float*)d_in[2];
  const float* Wv   = (const float*)d_in[3];
  const float* Wpk  = (const float*)d_in[4];
  const float* bpk  = (const float*)d_in[5];
  const float* Wpv  = (const float*)d_in[6];
  const float* bpv  = (const float*)d_in[7];
  const float* g1   = (const float*)d_in[8];
  const float* b1ln = (const float*)d_in[9];
  const float* W1   = (const float*)d_in[10];
  const float* b1   = (const float*)d_in[11];
  const float* W2   = (const float*)d_in[12];
  const float* b2   = (const float*)d_in[13];
  const float* g2   = (const float*)d_in[14];
  const float* b2ln = (const float*)d_in[15];

  char* wsb = (char*)d_ws;
  float* cosT = (float*)(wsb + 0);                //   256 KB
  float* sinT = (float*)(wsb + 262144);           //   256 KB
  float* srcf = (float*)(wsb + 524288);           // 32.77 MB fp32 residual
  u16* srcb   = (u16*)(wsb + 33292288);           // 16.38 MB bf16 mirror
  u16* Qb     = (u16*)(wsb + 49676288);           // 16.38 MB [8000][1024]
  u16* KTg    = (u16*)(wsb + 66060288);           // 16.78 MB [8][1024 d][1024 t]
  u16* VTg    = (u16*)(wsb + 82837504);           // 16.78 MB [8][1024 d][1024 t]
  u16* Km     = (u16*)(wsb + 99614720);           // 16.38 MB [8][1000][1024]
  u16* Vmt    = (u16*)(wsb + 115998720);          // 16.78 MB [8][1024 d][1024 u]
  u16* yB     = (u16*)(wsb + 132775936);          // 16.38 MB [8000][1024] bf16 y
  u16* wbuf   = (u16*)(wsb + 149159936);          // 27.07 MB layer weights
  u16* hB     = Qb;  // [8000][4096] overlaps Qb+KTg+VTg+Km (all dead at FFN time)

  u16* wqB  = wbuf + 0;          // [3072][1024] fused q,k,v
  u16* wpkB = wbuf + 3145728;    // [1000][1000]
  u16* wpvB = wbuf + 4145728;
  u16* w1B  = wbuf + 5145728;    // [4096][1024]
  u16* w2B  = wbuf + 9340032;    // [1024][4096]

  tab_kernel<<<250, 256, 0, stream>>>(cosT, sinT);
  zerotail_kernel<<<2304, 256, 0, stream>>>(KTg, VTg, Vmt);
  hipMemcpyAsync(srcf, x, (size_t)BT_ * D_ * sizeof(float), hipMemcpyDeviceToDevice, stream);
  convert_kernel<<<cdiv(BT_ * D_, 1024), 256, 0, stream>>>(x, srcb, BT_ * D_);

  for (int l = 0; l < 4; ++l) {
    convert_kernel<<<cdiv(1048576, 1024), 256, 0, stream>>>(Wq + (size_t)l * 1048576, wqB, 1048576);
    convert_kernel<<<cdiv(1048576, 1024), 256, 0, stream>>>(Wk + (size_t)l * 1048576, wqB + 1048576, 1048576);
    convert_kernel<<<cdiv(1048576, 1024), 256, 0, stream>>>(Wv + (size_t)l * 1048576, wqB + 2097152, 1048576);
    convert_kernel<<<cdiv(1000000, 1024), 256, 0, stream>>>(Wpk + (size_t)l * 1000000, wpkB, 1000000);
    convert_kernel<<<cdiv(1000000, 1024), 256, 0, stream>>>(Wpv + (size_t)l * 1000000, wpvB, 1000000);
    convert_kernel<<<cdiv(4194304, 1024), 256, 0, stream>>>(W1 + (size_t)l * 4194304, w1B, 4194304);
    convert_kernel<<<cdiv(4194304, 1024), 256, 0, stream>>>(W2 + (size_t)l * 4194304, w2B, 4194304);

    // Fused QKV, split epilogue: Q -> Qb, K^T -> KTg, V^T -> VTg
    gemm2p<0, false, true, true><<<dim3(24, 63, 1), 256, 0, stream>>>(
        srcb, wqB, Qb, nullptr, KTg, VTg, BT_, 3072, 1024, 1024, 1024, 1024, 0, 0, 0);

    // K position-mix: Km[b][u][d] = sum_t Wpk[u,t] KTg[b][d][t] + bpk[u]
    gemm2p<1, false, true, false><<<dim3(8, 8, 8), 256, 0, stream>>>(
        wpkB, KTg, Km, bpk + (size_t)l * 1000, nullptr, nullptr,
        1000, 1024, 1024, 1000, 1024, 1024, 0L, 1048576L, 1024000L);

    // V position-mix (transposed out): Vmt[b][d][u] = sum_t VTg[b][d][t] Wpv[u,t] + bpv[u]
    gemm2p<2, false, true, false><<<dim3(8, 8, 8), 256, 0, stream>>>(
        VTg, wpvB, Vmt, bpv + (size_t)l * 1000, nullptr, nullptr,
        1024, 1000, 1024, 1024, 1000, 1024, 1048576L, 0L, 1048576L);

    // Attention (rope fused on Q and K), bf16 out
    attn_kernel<<<dim3(8, 64), 256, 0, stream>>>(Qb, Km, Vmt, yB, cosT, sinT);

    addln_kernel<<<BT_, 256, 0, stream>>>(srcf, yB, g1 + (size_t)l * 1024,
                                          b1ln + (size_t)l * 1024, srcb);

    // FFN1 (+bias+gelu) -> bf16 h
    gemm2p<2, true, true, false><<<dim3(32, 63, 1), 256, 0, stream>>>(
        srcb, w1B, hB, b1 + (size_t)l * 4096, nullptr, nullptr,
        BT_, 4096, 1024, 1024, 1024, 4096, 0, 0, 0);
    // FFN2 (+bias) -> bf16 yB
    gemm2p<2, false, true, false><<<dim3(8, 63, 1), 256, 0, stream>>>(
        hB, w2B, yB, b2 + (size_t)l * 1024, nullptr, nullptr,
        BT_, 1024, 4096, 4096, 4096, 1024, 0, 0, 0);

    addln_kernel<<<BT_, 256, 0, stream>>>(srcf, yB, g2 + (size_t)l * 1024,
                                          b2ln + (size_t)l * 1024, srcb);
  }

  hipMemcpyAsync(d_out, srcf, (size_t)BT_ * D_ * sizeof(float), hipMemcpyDeviceToDevice, stream);
}